// Round 1
// baseline (1161.582 us; speedup 1.0000x reference)
//
#include <hip/hip_runtime.h>

// BotBlock pipeline on 8192 independent 4x4x64 "blocks" (raw-reshape semantics).
// Stage layout in ws (floats):
//   buf   : 8388608   (conv1 out -> overwritten in-place by attention out)
//   wT1   : 49152     conv1 weights transposed [c][o][tap pad12]
//   wT3   : 196608    conv3 weights transposed [c][o][tap pad12]
//   acc1/2/3 : raw BN sums (S, S2) per channel, zeroed via hipMemsetAsync

#define EPSV 1e-5f
#define INV_N (1.0f / 131072.0f)

__device__ __forceinline__ float bn_scale(const float* __restrict__ acc,
                                          const float* __restrict__ gam,
                                          const float* __restrict__ bet,
                                          int C, int c, float& shift) {
  float S = acc[c], S2 = acc[C + c];
  float mean = S * INV_N;
  float var  = S2 * INV_N - mean * mean;
  float rstd = rsqrtf(var + EPSV);
  float sc = gam[c] * rstd;
  shift = bet[c] - mean * sc;
  return sc;
}

// ---------------- weight transpose: [o][c][tap9] -> [c][o][tap pad12] ----------------
__global__ __launch_bounds__(256) void prep_kernel(const float* __restrict__ w1,
                                                   const float* __restrict__ w3,
                                                   float* __restrict__ wT1,
                                                   float* __restrict__ wT3) {
  int i = blockIdx.x * 256 + threadIdx.x;
  if (i < 36864) {                    // conv1: O=64, I=64
    int o = i / 576; int r = i - o * 576; int c = r / 9; int tap = r - c * 9;
    wT1[(c * 64 + o) * 12 + tap] = w1[i];
  } else if (i < 36864 + 147456) {    // conv3: O=256, I=64
    int j = i - 36864;
    int o = j / 576; int r = j - o * 576; int c = r / 9; int tap = r - c * 9;
    wT3[(c * 256 + o) * 12 + tap] = w3[j];
  }
}

// 30 FMAs for one input row (r) against taps (wx,wy,wz) = (dj=0,1,2)
#define CONV_ROW(wx, wy, wz, r)                                        \
  a1 = fmaf(wx, r.x, a1); a2 = fmaf(wx, r.y, a2); a3 = fmaf(wx, r.z, a3); \
  a0 = fmaf(wy, r.x, a0); a1 = fmaf(wy, r.y, a1); a2 = fmaf(wy, r.z, a2); a3 = fmaf(wy, r.w, a3); \
  a0 = fmaf(wz, r.y, a0); a1 = fmaf(wz, r.z, a1); a2 = fmaf(wz, r.w, a2);

// ---------------- conv1: [8192,64,4,4] -> [8192,64,4,4] ----------------
__global__ __launch_bounds__(256) void conv1_kernel(const float* __restrict__ x,
                                                    const float* __restrict__ wT,
                                                    const float* __restrict__ bias,
                                                    float* __restrict__ y1) {
  __shared__ float featp[64][24];     // 6 padded rows x 4 cols per channel
  const int b = blockIdx.x, t = threadIdx.x;
  const int o = t >> 2, g = t & 3;
  {
    const int c = t >> 2, seg = t & 3;
    float4 v = *reinterpret_cast<const float4*>(x + (size_t)b * 1024 + c * 16 + seg * 4);
    float* dst = &featp[c][(seg + 1) * 4];
    dst[0] = v.x; dst[1] = v.y; dst[2] = v.z; dst[3] = v.w;
    if (seg == 0) {
      float* z0 = &featp[c][0];  z0[0] = z0[1] = z0[2] = z0[3] = 0.f;
      float* z5 = &featp[c][20]; z5[0] = z5[1] = z5[2] = z5[3] = 0.f;
    }
  }
  __syncthreads();
  float a0 = 0.f, a1 = 0.f, a2 = 0.f, a3 = 0.f;
  for (int c = 0; c < 64; ++c) {
    const float4 r0 = *reinterpret_cast<const float4*>(&featp[c][g * 4]);
    const float4 r1 = *reinterpret_cast<const float4*>(&featp[c][g * 4 + 4]);
    const float4 r2 = *reinterpret_cast<const float4*>(&featp[c][g * 4 + 8]);
    const float* w = wT + ((c << 6) + o) * 12;
    const float4 wa = *reinterpret_cast<const float4*>(w);
    const float4 wb = *reinterpret_cast<const float4*>(w + 4);
    const float w22 = w[8];
    CONV_ROW(wa.x, wa.y, wa.z, r0)
    CONV_ROW(wa.w, wb.x, wb.y, r1)
    CONV_ROW(wb.z, wb.w, w22,  r2)
  }
  const float bo = bias[o];
  float4 outv; outv.x = a0 + bo; outv.y = a1 + bo; outv.z = a2 + bo; outv.w = a3 + bo;
  *reinterpret_cast<float4*>(y1 + (size_t)b * 1024 + t * 4) = outv;
}

// ---------------- BN stats: raw sums S, S2 per channel (atomic partials) ----------------
__global__ __launch_bounds__(256) void stats_kernel(const float* __restrict__ src, int C,
                                                    float* __restrict__ acc) {
  const int wg = blockIdx.x; const int c = wg >> 3; const int part = wg & 7;
  const int t = threadIdx.x;
  const size_t row = (size_t)C * 16;
  float s = 0.f, s2 = 0.f;
  for (int b = part * 1024 + t; b < part * 1024 + 1024; b += 256) {
    const float* p = src + (size_t)b * row + c * 16;
#pragma unroll
    for (int k = 0; k < 4; ++k) {
      float4 v = *reinterpret_cast<const float4*>(p + k * 4);
      s += v.x + v.y + v.z + v.w;
      s2 = fmaf(v.x, v.x, s2); s2 = fmaf(v.y, v.y, s2);
      s2 = fmaf(v.z, v.z, s2); s2 = fmaf(v.w, v.w, s2);
    }
  }
#pragma unroll
  for (int off = 32; off > 0; off >>= 1) {
    s  += __shfl_down(s, off);
    s2 += __shfl_down(s2, off);
  }
  __shared__ float red[8];
  const int w = t >> 6;
  if ((t & 63) == 0) { red[w] = s; red[4 + w] = s2; }
  __syncthreads();
  if (t == 0) {
    float S  = red[0] + red[1] + red[2] + red[3];
    float S2 = red[4] + red[5] + red[6] + red[7];
    atomicAdd(&acc[c], S);
    atomicAdd(&acc[C + c], S2);
  }
}

// ---------------- BN1+relu -> qkv -> rel-pos attention -> write o (in-place) ----------------
__global__ __launch_bounds__(64) void attn_kernel(float* __restrict__ buf,
                                                  const float* __restrict__ wq,
                                                  const float* __restrict__ wk,
                                                  const float* __restrict__ wv,
                                                  const float* __restrict__ relw,
                                                  const float* __restrict__ relh,
                                                  const float* __restrict__ acc1,
                                                  const float* __restrict__ g1,
                                                  const float* __restrict__ b1) {
  __shared__ float feat[16][64];                 // [pos][c], BN1+relu applied
  __shared__ float qs[4][16][17], ks[4][16][17], vs[4][16][17];  // pad 17 vs bank conflicts
  const int b = blockIdx.x, t = threadIdx.x;
  {
    const int c = t;
    float sh; const float sc = bn_scale(acc1, g1, b1, 64, c, sh);
#pragma unroll
    for (int pp = 0; pp < 4; ++pp) {
      float4 v = *reinterpret_cast<const float4*>(buf + (size_t)b * 1024 + c * 16 + pp * 4);
      feat[pp * 4 + 0][c] = fmaxf(fmaf(v.x, sc, sh), 0.f);
      feat[pp * 4 + 1][c] = fmaxf(fmaf(v.y, sc, sh), 0.f);
      feat[pp * 4 + 2][c] = fmaxf(fmaf(v.z, sc, sh), 0.f);
      feat[pp * 4 + 3][c] = fmaxf(fmaf(v.w, sc, sh), 0.f);
    }
  }
  __syncthreads();
  const int n = t >> 4, dd = t & 15;
  {
    const float* wqp = wq + (n << 4) + dd;       // stride 64 over c
    const float* wkp = wk + (n << 4) + dd;
    const float* wvp = wv + (n << 4) + dd;
    for (int p = 0; p < 16; ++p) {
      float aq = 0.f, ak = 0.f, av = 0.f;
      for (int c = 0; c < 64; ++c) {
        const float f = feat[p][c];
        aq = fmaf(f, wqp[c << 6], aq);
        ak = fmaf(f, wkp[c << 6], ak);
        av = fmaf(f, wvp[c << 6], av);
      }
      qs[n][p][dd] = aq * 0.25f;                 // d^-0.5, d=16
      ks[n][p][dd] = ak;
      vs[n][p][dd] = av;
    }
  }
  __syncthreads();
  const int qp = t & 15, qi = qp >> 2, qj = qp & 3;
  float q_[16];
#pragma unroll
  for (int d2 = 0; d2 < 16; ++d2) q_[d2] = qs[n][qp][d2];
  float rw[7], rhh[7];
#pragma unroll
  for (int m = 0; m < 7; ++m) {
    float s1 = 0.f, s2 = 0.f;
#pragma unroll
    for (int d2 = 0; d2 < 16; ++d2) {
      s1 = fmaf(q_[d2], relw[m * 16 + d2], s1);
      s2 = fmaf(q_[d2], relh[m * 16 + d2], s2);
    }
    rw[m] = s1; rhh[m] = s2;
  }
  float lo[16]; float mx = -1e30f;
#pragma unroll
  for (int kp = 0; kp < 16; ++kp) {
    float s = rw[(kp & 3) - qj + 3] + rhh[(kp >> 2) - qi + 3];
#pragma unroll
    for (int d2 = 0; d2 < 16; ++d2) s = fmaf(q_[d2], ks[n][kp][d2], s);
    lo[kp] = s; mx = fmaxf(mx, s);
  }
  float ssum = 0.f;
#pragma unroll
  for (int kp = 0; kp < 16; ++kp) { float e = __expf(lo[kp] - mx); lo[kp] = e; ssum += e; }
  const float inv = 1.0f / ssum;
#pragma unroll
  for (int d2 = 0; d2 < 16; ++d2) {
    float s = 0.f;
#pragma unroll
    for (int kp = 0; kp < 16; ++kp) s = fmaf(lo[kp], vs[n][kp][d2], s);
    buf[(size_t)b * 1024 + ((n << 4) + d2) * 16 + qp] = s * inv;   // NCHW in block space
  }
}

// ---------------- BN2+relu -> conv3 -> y3 (=d_out, pre-BN3) ----------------
__global__ __launch_bounds__(256) void conv3_kernel(const float* __restrict__ obuf,
                                                    const float* __restrict__ wT,
                                                    const float* __restrict__ bias,
                                                    const float* __restrict__ acc2,
                                                    const float* __restrict__ g2,
                                                    const float* __restrict__ b2,
                                                    float* __restrict__ y3) {
  __shared__ float featp[64][24];
  const int b = blockIdx.x, t = threadIdx.x;
  const int o0 = t >> 2, g = t & 3;
  {
    const int c = t >> 2, seg = t & 3;
    float sh; const float sc = bn_scale(acc2, g2, b2, 64, c, sh);
    float4 v = *reinterpret_cast<const float4*>(obuf + (size_t)b * 1024 + c * 16 + seg * 4);
    float* dst = &featp[c][(seg + 1) * 4];
    dst[0] = fmaxf(fmaf(v.x, sc, sh), 0.f);
    dst[1] = fmaxf(fmaf(v.y, sc, sh), 0.f);
    dst[2] = fmaxf(fmaf(v.z, sc, sh), 0.f);
    dst[3] = fmaxf(fmaf(v.w, sc, sh), 0.f);
    if (seg == 0) {
      float* z0 = &featp[c][0];  z0[0] = z0[1] = z0[2] = z0[3] = 0.f;
      float* z5 = &featp[c][20]; z5[0] = z5[1] = z5[2] = z5[3] = 0.f;
    }
  }
  __syncthreads();
  float acc[4][4];
#pragma unroll
  for (int i = 0; i < 4; ++i)
#pragma unroll
    for (int j = 0; j < 4; ++j) acc[i][j] = 0.f;
  for (int c = 0; c < 64; ++c) {
    const float4 r0 = *reinterpret_cast<const float4*>(&featp[c][g * 4]);
    const float4 r1 = *reinterpret_cast<const float4*>(&featp[c][g * 4 + 4]);
    const float4 r2 = *reinterpret_cast<const float4*>(&featp[c][g * 4 + 8]);
#pragma unroll
    for (int oo = 0; oo < 4; ++oo) {
      const int o = (oo << 6) + o0;
      const float* w = wT + ((c << 8) + o) * 12;
      const float4 wa = *reinterpret_cast<const float4*>(w);
      const float4 wb = *reinterpret_cast<const float4*>(w + 4);
      const float w22 = w[8];
      float a0 = acc[oo][0], a1 = acc[oo][1], a2 = acc[oo][2], a3 = acc[oo][3];
      CONV_ROW(wa.x, wa.y, wa.z, r0)
      CONV_ROW(wa.w, wb.x, wb.y, r1)
      CONV_ROW(wb.z, wb.w, w22,  r2)
      acc[oo][0] = a0; acc[oo][1] = a1; acc[oo][2] = a2; acc[oo][3] = a3;
    }
  }
#pragma unroll
  for (int oo = 0; oo < 4; ++oo) {
    const int o = (oo << 6) + o0;
    const float bo = bias[o];
    float4 outv;
    outv.x = acc[oo][0] + bo; outv.y = acc[oo][1] + bo;
    outv.z = acc[oo][2] + bo; outv.w = acc[oo][3] + bo;
    *reinterpret_cast<float4*>(y3 + (size_t)b * 4096 + (size_t)o * 16 + g * 4) = outv;
  }
}

// ---------------- BN3 + relu, in-place on d_out ----------------
__global__ __launch_bounds__(256) void final_kernel(float* __restrict__ out,
                                                    const float* __restrict__ acc3,
                                                    const float* __restrict__ g3,
                                                    const float* __restrict__ b3) {
  const size_t i = ((size_t)blockIdx.x * 256 + threadIdx.x) * 4;
  const int c = (int)((i >> 4) & 255);
  float sh; const float sc = bn_scale(acc3, g3, b3, 256, c, sh);
  float4 v = *reinterpret_cast<float4*>(out + i);
  v.x = fmaxf(fmaf(v.x, sc, sh), 0.f);
  v.y = fmaxf(fmaf(v.y, sc, sh), 0.f);
  v.z = fmaxf(fmaf(v.z, sc, sh), 0.f);
  v.w = fmaxf(fmaf(v.w, sc, sh), 0.f);
  *reinterpret_cast<float4*>(out + i) = v;
}

extern "C" void kernel_launch(void* const* d_in, const int* in_sizes, int n_in,
                              void* d_out, int out_size, void* d_ws, size_t ws_size,
                              hipStream_t stream) {
  const float* x   = (const float*)d_in[0];
  const float* w1  = (const float*)d_in[1];
  const float* b1c = (const float*)d_in[2];
  const float* g1  = (const float*)d_in[3];
  const float* bb1 = (const float*)d_in[4];
  const float* wq  = (const float*)d_in[5];
  const float* wk  = (const float*)d_in[6];
  const float* wv  = (const float*)d_in[7];
  const float* rw  = (const float*)d_in[8];
  const float* rh  = (const float*)d_in[9];
  const float* g2  = (const float*)d_in[10];
  const float* bb2 = (const float*)d_in[11];
  const float* w3  = (const float*)d_in[12];
  const float* b3c = (const float*)d_in[13];
  const float* g3  = (const float*)d_in[14];
  const float* bb3 = (const float*)d_in[15];
  float* out = (float*)d_out;
  float* ws  = (float*)d_ws;

  float* buf  = ws;                 // 8388608 floats
  float* wT1  = ws + 8388608;       // 49152
  float* wT3  = wT1 + 49152;        // 196608
  float* acc1 = wT3 + 196608;       // 128
  float* acc2 = acc1 + 128;         // 128
  float* acc3 = acc2 + 128;         // 512

  hipMemsetAsync(acc1, 0, (128 + 128 + 512) * sizeof(float), stream);
  prep_kernel<<<720, 256, 0, stream>>>(w1, w3, wT1, wT3);
  conv1_kernel<<<8192, 256, 0, stream>>>(x, wT1, b1c, buf);
  stats_kernel<<<512, 256, 0, stream>>>(buf, 64, acc1);
  attn_kernel<<<8192, 64, 0, stream>>>(buf, wq, wk, wv, rw, rh, acc1, g1, bb1);
  stats_kernel<<<512, 256, 0, stream>>>(buf, 64, acc2);
  conv3_kernel<<<8192, 256, 0, stream>>>(buf, wT3, b3c, acc2, g2, bb2, out);
  stats_kernel<<<2048, 256, 0, stream>>>(out, 256, acc3);
  final_kernel<<<32768, 256, 0, stream>>>(out, acc3, g3, bb3);
}

// Round 2
// 356.105 us; speedup vs baseline: 3.2619x; 3.2619x over previous
//
#include <hip/hip_runtime.h>
#include <stdint.h>

// BotBlock pipeline, MFMA version.
// Block space: 8192 independent 4x4x64 blocks (raw-reshape semantics).
// buf (ws) is NHWC in block space: buf[row*64 + c], row = b*16 + p.
// d_out NCHW block space: out[b*4096 + o*16 + p].
// Convs = im2col GEMMs, K = 576 (9 taps x 64 ch), bf16 MFMA 16x16x32, fp32 acc.

#define EPSV 1e-5f
#define INV_N (1.0f / 131072.0f)

typedef unsigned short u16;
typedef __attribute__((ext_vector_type(8))) short short8b;  // 8 bf16
typedef __attribute__((ext_vector_type(4))) float f32x4;

__device__ __forceinline__ u16 f2bf(float f) {
  unsigned u = __float_as_uint(f);
  u += 0x7fffu + ((u >> 16) & 1u);
  return (u16)(u >> 16);
}

__device__ __forceinline__ float bn_scale(const float* __restrict__ acc,
                                          const float* __restrict__ gam,
                                          const float* __restrict__ bet,
                                          int C, int c, float& shift) {
  float S = acc[c], S2 = acc[C + c];
  float mean = S * INV_N;
  float var  = S2 * INV_N - mean * mean;
  float rstd = rsqrtf(var + EPSV);
  float sc = gam[c] * rstd;
  shift = bet[c] - mean * sc;
  return sc;
}

// ---------- prep: weights -> bf16 chunked [18][O][40] (k-contiguous, pad 32..39=0) ----------
__global__ __launch_bounds__(256) void prep_kernel(const float* __restrict__ w1,
                                                   const float* __restrict__ w3,
                                                   u16* __restrict__ wp1,
                                                   u16* __restrict__ wp3) {
  int i = blockIdx.x * 256 + threadIdx.x;
  const int tot1 = 18 * 64 * 40;
  const int tot3 = 18 * 256 * 40;
  if (i < tot1) {
    int ch = i / (64 * 40); int r = i - ch * 64 * 40; int o = r / 40; int kk = r - o * 40;
    float v = 0.f;
    if (kk < 32) { int k = ch * 32 + kk; int tap = k >> 6; int c = k & 63;
                   v = w1[o * 576 + c * 9 + tap]; }
    wp1[i] = f2bf(v);
  } else if (i < tot1 + tot3) {
    int j = i - tot1;
    int ch = j / (256 * 40); int r = j - ch * 256 * 40; int o = r / 40; int kk = r - o * 40;
    float v = 0.f;
    if (kk < 32) { int k = ch * 32 + kk; int tap = k >> 6; int c = k & 63;
                   v = w3[o * 576 + c * 9 + tap]; }
    wp3[j] = f2bf(v);
  }
}

// ---------- conv1: x (NCHW blocks, fp32) -> buf (NHWC, fp32). M=rows(256), N=o(64) ----------
__global__ __launch_bounds__(256) void conv1_kernel(const float* __restrict__ x,
                                                    const u16* __restrict__ wp,
                                                    float* __restrict__ buf) {
  __shared__ char featA[257 * 128];       // bf16 [row][64ch], XOR-swizzled; row 256 = zeros
  __shared__ char ldsW[2][64 * 80];       // [o][40 bf16] per 32-k chunk
  const int t = threadIdx.x;
  const int lane = t & 63, w = t >> 6;
  const int lrow = lane & 15, lk = lane >> 4;
  const int wm = w >> 1, wn = w & 1;      // wave tile: 128 rows x 32 o
  const size_t Mbase = (size_t)blockIdx.x * 256;

  // per-lane tap offsets (p = lrow): rel = valid ? p'*128 : huge (clamped to zero row)
  int rel[9];
  {
    const int pi = lrow >> 2, pj = lrow & 3;
#pragma unroll
    for (int tap = 0; tap < 9; ++tap) {
      const int ti = tap / 3, tj = tap - ti * 3;
      int si = pi + ti - 1, sj = pj + tj - 1;
      bool valid = ((unsigned)si < 4u) && ((unsigned)sj < 4u);
      rel[tap] = valid ? ((si * 4 + sj) << 7) : (1 << 24);
    }
  }

  // stage featA: 16 blocks = 16384 floats NCHW -> bf16 [row][c] swizzled
#pragma unroll
  for (int i = 0; i < 16; ++i) {
    float4 v = *reinterpret_cast<const float4*>(x + Mbase * 64 + i * 1024 + t * 4);
    const int c = t >> 2, p0 = (t & 3) * 4;
    float vv[4] = {v.x, v.y, v.z, v.w};
#pragma unroll
    for (int j = 0; j < 4; ++j) {
      int row = i * 16 + p0 + j;
      int byte = row * 128 + ((((c >> 3) ^ (row & 7)) << 4) | ((c & 7) << 1));
      *reinterpret_cast<u16*>(featA + byte) = f2bf(vv[j]);
    }
  }
  if (t < 8) *reinterpret_cast<uint4*>(featA + 256 * 128 + t * 16) = uint4{0, 0, 0, 0};

  // W chunk staging (320 granules of 16B per chunk)
  uint4 s0, s1;
  {
    const u16* sp = wp;                       // chunk 0
    s0 = *reinterpret_cast<const uint4*>(sp + (size_t)t * 8);
    if (t < 64) s1 = *reinterpret_cast<const uint4*>(sp + (size_t)(t + 256) * 8);
    *reinterpret_cast<uint4*>(ldsW[0] + t * 16) = s0;
    if (t < 64) *reinterpret_cast<uint4*>(ldsW[0] + (t + 256) * 16) = s1;
  }
  __syncthreads();

  f32x4 acc[8][2] = {};
#pragma unroll
  for (int chn = 0; chn < 18; ++chn) {
    const int cur = chn & 1;
    const int tap = chn >> 1, kk = chn & 1;
    if (chn + 1 < 18) {                      // issue next chunk loads early
      const u16* sp = wp + (chn + 1) * 2560;
      s0 = *reinterpret_cast<const uint4*>(sp + (size_t)t * 8);
      if (t < 64) s1 = *reinterpret_cast<const uint4*>(sp + (size_t)(t + 256) * 8);
    }
    const int kkg = (kk << 6) | (lk << 4);
    short8b bw[2];
#pragma unroll
    for (int n = 0; n < 2; ++n)
      bw[n] = *reinterpret_cast<const short8b*>(ldsW[cur] + (wn * 32 + n * 16 + lrow) * 80 + lk * 16);
#pragma unroll
    for (int m = 0; m < 8; ++m) {
      int ad = ((wm * 128 + m * 16) << 7) + rel[tap];
      ad = ad < 32768 ? ad : 32768;          // invalid -> zero row
      ad += (kkg ^ ((ad >> 3) & 0x70));      // XOR swizzle (row&7)
      short8b af = *reinterpret_cast<const short8b*>(featA + ad);
#pragma unroll
      for (int n = 0; n < 2; ++n)
        acc[m][n] = __builtin_amdgcn_mfma_f32_16x16x32_bf16(af, bw[n], acc[m][n], 0, 0, 0);
    }
    if (chn + 1 < 18) {                      // write next chunk (other buffer)
      *reinterpret_cast<uint4*>(ldsW[cur ^ 1] + t * 16) = s0;
      if (t < 64) *reinterpret_cast<uint4*>(ldsW[cur ^ 1] + (t + 256) * 16) = s1;
    }
    __syncthreads();
  }

  // epilogue: D[row][o] -> buf NHWC (16 lanes = 64B contiguous)
#pragma unroll
  for (int m = 0; m < 8; ++m) {
    const size_t rowg0 = Mbase + wm * 128 + m * 16 + lk * 4;
#pragma unroll
    for (int n = 0; n < 2; ++n) {
      const int o = wn * 32 + n * 16 + lrow;
#pragma unroll
      for (int r = 0; r < 4; ++r)
        buf[(rowg0 + r) * 64 + o] = acc[m][n][r];
    }
  }
}

// ---------- per-channel stats on NHWC buf (C=64): raw S, S2 ----------
__global__ __launch_bounds__(256) void stats_nhwc(const float* __restrict__ src,
                                                  float* __restrict__ acc) {
  const int t = threadIdx.x;
  const int cq = t & 15, ro = t >> 4;
  const size_t base = (size_t)blockIdx.x * 512 + ro;
  float4 s = {0, 0, 0, 0}, s2 = {0, 0, 0, 0};
  for (int i = 0; i < 32; ++i) {
    float4 v = *reinterpret_cast<const float4*>(src + (base + (size_t)i * 16) * 64 + cq * 4);
    s.x += v.x; s.y += v.y; s.z += v.z; s.w += v.w;
    s2.x = fmaf(v.x, v.x, s2.x); s2.y = fmaf(v.y, v.y, s2.y);
    s2.z = fmaf(v.z, v.z, s2.z); s2.w = fmaf(v.w, v.w, s2.w);
  }
#pragma unroll
  for (int off = 32; off >= 16; off >>= 1) {
    s.x += __shfl_down(s.x, off); s.y += __shfl_down(s.y, off);
    s.z += __shfl_down(s.z, off); s.w += __shfl_down(s.w, off);
    s2.x += __shfl_down(s2.x, off); s2.y += __shfl_down(s2.y, off);
    s2.z += __shfl_down(s2.z, off); s2.w += __shfl_down(s2.w, off);
  }
  __shared__ float red[4][16][8];
  const int wv = t >> 6, lane = t & 63;
  if (lane < 16) {
    float* r = red[wv][lane];
    r[0] = s.x; r[1] = s.y; r[2] = s.z; r[3] = s.w;
    r[4] = s2.x; r[5] = s2.y; r[6] = s2.z; r[7] = s2.w;
  }
  __syncthreads();
  if (wv == 0 && lane < 16) {
#pragma unroll
    for (int j = 0; j < 4; ++j) {
      float S = red[0][lane][j] + red[1][lane][j] + red[2][lane][j] + red[3][lane][j];
      float S2 = red[0][lane][4 + j] + red[1][lane][4 + j] + red[2][lane][4 + j] + red[3][lane][4 + j];
      atomicAdd(&acc[lane * 4 + j], S);
      atomicAdd(&acc[64 + lane * 4 + j], S2);
    }
  }
}

// ---------- stats on NCHW d_out (C=256) ----------
__global__ __launch_bounds__(256) void stats_kernel(const float* __restrict__ src, int C,
                                                    float* __restrict__ acc) {
  const int wg = blockIdx.x; const int c = wg >> 3; const int part = wg & 7;
  const int t = threadIdx.x;
  const size_t row = (size_t)C * 16;
  float s = 0.f, s2 = 0.f;
  for (int b = part * 1024 + t; b < part * 1024 + 1024; b += 256) {
    const float* p = src + (size_t)b * row + c * 16;
#pragma unroll
    for (int k = 0; k < 4; ++k) {
      float4 v = *reinterpret_cast<const float4*>(p + k * 4);
      s += v.x + v.y + v.z + v.w;
      s2 = fmaf(v.x, v.x, s2); s2 = fmaf(v.y, v.y, s2);
      s2 = fmaf(v.z, v.z, s2); s2 = fmaf(v.w, v.w, s2);
    }
  }
#pragma unroll
  for (int off = 32; off > 0; off >>= 1) {
    s  += __shfl_down(s, off);
    s2 += __shfl_down(s2, off);
  }
  __shared__ float red[8];
  const int wv = t >> 6;
  if ((t & 63) == 0) { red[wv] = s; red[4 + wv] = s2; }
  __syncthreads();
  if (t == 0) {
    float S  = red[0] + red[1] + red[2] + red[3];
    float S2 = red[4] + red[5] + red[6] + red[7];
    atomicAdd(&acc[c], S);
    atomicAdd(&acc[C + c], S2);
  }
}

// ---------- BN1+relu -> qkv -> rel-pos attention -> write back (NHWC, in-place) ----------
__global__ __launch_bounds__(64) void attn_kernel(float* __restrict__ buf,
                                                  const float* __restrict__ wq,
                                                  const float* __restrict__ wk,
                                                  const float* __restrict__ wv,
                                                  const float* __restrict__ relw,
                                                  const float* __restrict__ relh,
                                                  const float* __restrict__ acc1,
                                                  const float* __restrict__ g1,
                                                  const float* __restrict__ b1) {
  __shared__ float feat[16][64];
  __shared__ float qs[4][16][17], ks[4][16][17], vs[4][16][17];
  const int b = blockIdx.x, t = threadIdx.x;
  {
    const int c = t;
    float sh; const float sc = bn_scale(acc1, g1, b1, 64, c, sh);
#pragma unroll
    for (int p = 0; p < 16; ++p) {
      float v = buf[(size_t)b * 1024 + p * 64 + c];
      feat[p][c] = fmaxf(fmaf(v, sc, sh), 0.f);
    }
  }
  __syncthreads();
  const int n = t >> 4, dd = t & 15;
  {
    const float* wqp = wq + (n << 4) + dd;
    const float* wkp = wk + (n << 4) + dd;
    const float* wvp = wv + (n << 4) + dd;
    for (int p = 0; p < 16; ++p) {
      float aq = 0.f, ak = 0.f, av = 0.f;
      for (int c = 0; c < 64; ++c) {
        const float f = feat[p][c];
        aq = fmaf(f, wqp[c << 6], aq);
        ak = fmaf(f, wkp[c << 6], ak);
        av = fmaf(f, wvp[c << 6], av);
      }
      qs[n][p][dd] = aq * 0.25f;
      ks[n][p][dd] = ak;
      vs[n][p][dd] = av;
    }
  }
  __syncthreads();
  const int qp = t & 15, qi = qp >> 2, qj = qp & 3;
  float q_[16];
#pragma unroll
  for (int d2 = 0; d2 < 16; ++d2) q_[d2] = qs[n][qp][d2];
  float rw[7], rhh[7];
#pragma unroll
  for (int m = 0; m < 7; ++m) {
    float a1 = 0.f, a2 = 0.f;
#pragma unroll
    for (int d2 = 0; d2 < 16; ++d2) {
      a1 = fmaf(q_[d2], relw[m * 16 + d2], a1);
      a2 = fmaf(q_[d2], relh[m * 16 + d2], a2);
    }
    rw[m] = a1; rhh[m] = a2;
  }
  float lo[16]; float mx = -1e30f;
#pragma unroll
  for (int kp = 0; kp < 16; ++kp) {
    float sacc = rw[(kp & 3) - qj + 3] + rhh[(kp >> 2) - qi + 3];
#pragma unroll
    for (int d2 = 0; d2 < 16; ++d2) sacc = fmaf(q_[d2], ks[n][kp][d2], sacc);
    lo[kp] = sacc; mx = fmaxf(mx, sacc);
  }
  float ssum = 0.f;
#pragma unroll
  for (int kp = 0; kp < 16; ++kp) { float e = __expf(lo[kp] - mx); lo[kp] = e; ssum += e; }
  const float inv = 1.0f / ssum;
  float ov[16];
#pragma unroll
  for (int d2 = 0; d2 < 16; ++d2) {
    float sacc = 0.f;
#pragma unroll
    for (int kp = 0; kp < 16; ++kp) sacc = fmaf(lo[kp], vs[n][kp][d2], sacc);
    ov[d2] = sacc * inv;
  }
  float* dst = buf + (size_t)b * 1024 + qp * 64 + (n << 4);
#pragma unroll
  for (int d4 = 0; d4 < 4; ++d4) {
    float4 vv = {ov[4 * d4], ov[4 * d4 + 1], ov[4 * d4 + 2], ov[4 * d4 + 3]};
    *reinterpret_cast<float4*>(dst + 4 * d4) = vv;
  }
}

// ---------- conv3: BN2+relu(buf NHWC) -> d_out NCHW. M=o(128 half), N=rows(128) ----------
__global__ __launch_bounds__(256) void conv3_kernel(const float* __restrict__ src,
                                                    const u16* __restrict__ wp,
                                                    const float* __restrict__ acc2,
                                                    const float* __restrict__ g2,
                                                    const float* __restrict__ b2,
                                                    float* __restrict__ out) {
  __shared__ char featB[129 * 128];        // bf16 [row][64ch] swizzled; row 128 = zeros
  __shared__ char ldsW[2][128 * 80];       // [o 128][40 bf16] per chunk
  __shared__ float scsh[128];
  const int t = threadIdx.x;
  const int lane = t & 63, w = t >> 6;
  const int lrow = lane & 15, lk = lane >> 4;
  const int wm = w >> 1, wn = w & 1;       // wave tile: 64 o x 64 rows
  const int Nbase = blockIdx.x * 128;
  const int ohalf = blockIdx.y;            // 0/1 -> o 0..127 / 128..255

  int rel[9];
  {
    const int pi = lrow >> 2, pj = lrow & 3;
#pragma unroll
    for (int tap = 0; tap < 9; ++tap) {
      const int ti = tap / 3, tj = tap - ti * 3;
      int si = pi + ti - 1, sj = pj + tj - 1;
      bool valid = ((unsigned)si < 4u) && ((unsigned)sj < 4u);
      rel[tap] = valid ? ((si * 4 + sj) << 7) : (1 << 24);
    }
  }

  if (t < 64) {
    float sh; float sc = bn_scale(acc2, g2, b2, 64, t, sh);
    scsh[t * 2] = sc; scsh[t * 2 + 1] = sh;
  }
  __syncthreads();

  // stage featB with BN2+relu
  {
    const int row = t >> 1, q2 = t & 1;
    const float* p = src + (size_t)(Nbase + row) * 64 + q2 * 32;
#pragma unroll
    for (int gg = 0; gg < 4; ++gg) {
      float4 a = *reinterpret_cast<const float4*>(p + gg * 8);
      float4 bq = *reinterpret_cast<const float4*>(p + gg * 8 + 4);
      const int cb = q2 * 32 + gg * 8;
      union { u16 h[8]; uint4 u; } pk;
      float va[8] = {a.x, a.y, a.z, a.w, bq.x, bq.y, bq.z, bq.w};
#pragma unroll
      for (int j = 0; j < 8; ++j)
        pk.h[j] = f2bf(fmaxf(fmaf(va[j], scsh[(cb + j) * 2], scsh[(cb + j) * 2 + 1]), 0.f));
      const int g = (q2 * 4 + gg) ^ (row & 7);
      *reinterpret_cast<uint4*>(featB + row * 128 + g * 16) = pk.u;
    }
  }
  if (t < 8) *reinterpret_cast<uint4*>(featB + 128 * 128 + t * 16) = uint4{0, 0, 0, 0};

  // W staging: 640 granules per chunk (this o-half)
  uint4 s0, s1, s2v;
  {
    const u16* sp = wp + (size_t)ohalf * 5120;    // chunk 0
    s0 = *reinterpret_cast<const uint4*>(sp + (size_t)t * 8);
    s1 = *reinterpret_cast<const uint4*>(sp + (size_t)(t + 256) * 8);
    if (t < 128) s2v = *reinterpret_cast<const uint4*>(sp + (size_t)(t + 512) * 8);
    *reinterpret_cast<uint4*>(ldsW[0] + t * 16) = s0;
    *reinterpret_cast<uint4*>(ldsW[0] + (t + 256) * 16) = s1;
    if (t < 128) *reinterpret_cast<uint4*>(ldsW[0] + (t + 512) * 16) = s2v;
  }
  __syncthreads();

  f32x4 acc[4][4] = {};
#pragma unroll
  for (int chn = 0; chn < 18; ++chn) {
    const int cur = chn & 1;
    const int tap = chn >> 1, kk = chn & 1;
    if (chn + 1 < 18) {
      const u16* sp = wp + (size_t)(chn + 1) * 10240 + (size_t)ohalf * 5120;
      s0 = *reinterpret_cast<const uint4*>(sp + (size_t)t * 8);
      s1 = *reinterpret_cast<const uint4*>(sp + (size_t)(t + 256) * 8);
      if (t < 128) s2v = *reinterpret_cast<const uint4*>(sp + (size_t)(t + 512) * 8);
    }
    const int kkg = (kk << 6) | (lk << 4);
    short8b aw[4];
#pragma unroll
    for (int m = 0; m < 4; ++m)
      aw[m] = *reinterpret_cast<const short8b*>(ldsW[cur] + (wm * 64 + m * 16 + lrow) * 80 + lk * 16);
    short8b bf[4];
#pragma unroll
    for (int n = 0; n < 4; ++n) {
      int ad = ((wn * 64 + n * 16) << 7) + rel[tap];
      ad = ad < 16384 ? ad : 16384;
      ad += (kkg ^ ((ad >> 3) & 0x70));
      bf[n] = *reinterpret_cast<const short8b*>(featB + ad);
    }
#pragma unroll
    for (int m = 0; m < 4; ++m)
#pragma unroll
      for (int n = 0; n < 4; ++n)
        acc[m][n] = __builtin_amdgcn_mfma_f32_16x16x32_bf16(aw[m], bf[n], acc[m][n], 0, 0, 0);
    if (chn + 1 < 18) {
      *reinterpret_cast<uint4*>(ldsW[cur ^ 1] + t * 16) = s0;
      *reinterpret_cast<uint4*>(ldsW[cur ^ 1] + (t + 256) * 16) = s1;
      if (t < 128) *reinterpret_cast<uint4*>(ldsW[cur ^ 1] + (t + 512) * 16) = s2v;
    }
    __syncthreads();
  }

  // epilogue: D[o][row] -> out NCHW (16 lanes = contiguous 64B per (b,o))
#pragma unroll
  for (int m = 0; m < 4; ++m) {
    const int o = ohalf * 128 + wm * 64 + m * 16 + lk * 4;
#pragma unroll
    for (int n = 0; n < 4; ++n) {
      const int colg = Nbase + wn * 64 + n * 16 + lrow;
      const int b = colg >> 4, p = colg & 15;
      float* dst = out + (size_t)b * 4096 + p;
#pragma unroll
      for (int r = 0; r < 4; ++r)
        dst[(o + r) * 16] = acc[m][n][r];
    }
  }
}

// ---------- BN3 + relu in-place on d_out ----------
__global__ __launch_bounds__(256) void final_kernel(float* __restrict__ out,
                                                    const float* __restrict__ acc3,
                                                    const float* __restrict__ g3,
                                                    const float* __restrict__ b3) {
  const size_t i = ((size_t)blockIdx.x * 256 + threadIdx.x) * 4;
  const int c = (int)((i >> 4) & 255);
  float sh; const float sc = bn_scale(acc3, g3, b3, 256, c, sh);
  float4 v = *reinterpret_cast<float4*>(out + i);
  v.x = fmaxf(fmaf(v.x, sc, sh), 0.f);
  v.y = fmaxf(fmaf(v.y, sc, sh), 0.f);
  v.z = fmaxf(fmaf(v.z, sc, sh), 0.f);
  v.w = fmaxf(fmaf(v.w, sc, sh), 0.f);
  *reinterpret_cast<float4*>(out + i) = v;
}

extern "C" void kernel_launch(void* const* d_in, const int* in_sizes, int n_in,
                              void* d_out, int out_size, void* d_ws, size_t ws_size,
                              hipStream_t stream) {
  const float* x   = (const float*)d_in[0];
  const float* w1  = (const float*)d_in[1];
  const float* g1  = (const float*)d_in[3];
  const float* bb1 = (const float*)d_in[4];
  const float* wq  = (const float*)d_in[5];
  const float* wk  = (const float*)d_in[6];
  const float* wv  = (const float*)d_in[7];
  const float* rw  = (const float*)d_in[8];
  const float* rh  = (const float*)d_in[9];
  const float* g2  = (const float*)d_in[10];
  const float* bb2 = (const float*)d_in[11];
  const float* w3  = (const float*)d_in[12];
  const float* g3  = (const float*)d_in[14];
  const float* bb3 = (const float*)d_in[15];
  float* out = (float*)d_out;
  float* ws  = (float*)d_ws;

  float* buf  = ws;                                  // 8388608 floats
  u16*   wp1  = (u16*)(ws + 8388608);                // 46080 u16
  u16*   wp3  = wp1 + 46080;                         // 184320 u16
  float* acc1 = ws + 8388608 + 23040 + 92160;        // 128
  float* acc2 = acc1 + 128;                          // 128
  float* acc3 = acc2 + 128;                          // 512

  hipMemsetAsync(acc1, 0, (128 + 128 + 512) * sizeof(float), stream);
  prep_kernel<<<900, 256, 0, stream>>>(w1, w3, wp1, wp3);
  conv1_kernel<<<512, 256, 0, stream>>>(x, wp1, buf);
  stats_nhwc<<<256, 256, 0, stream>>>(buf, acc1);
  attn_kernel<<<8192, 64, 0, stream>>>(buf, wq, wk, wv, rw, rh, acc1, g1, bb1);
  stats_nhwc<<<256, 256, 0, stream>>>(buf, acc2);
  conv3_kernel<<<dim3(1024, 2), 256, 0, stream>>>(buf, wp3, acc2, g2, bb2, out);
  stats_kernel<<<2048, 256, 0, stream>>>(out, 256, acc3);
  final_kernel<<<32768, 256, 0, stream>>>(out, acc3, g3, bb3);
}

// Round 3
// 253.266 us; speedup vs baseline: 4.5864x; 1.4061x over previous
//
#include <hip/hip_runtime.h>
#include <stdint.h>

// BotBlock pipeline, MFMA version (round 3).
// Block space: 8192 independent 4x4x64 blocks (raw-reshape semantics).
// buf (ws) is NHWC in block space: buf[row*64 + c], row = b*16 + p.
// d_out NCHW block space: out[b*4096 + o*16 + p].
// Convs = im2col GEMMs, K = 576 (9 taps x 64 ch), bf16 MFMA 16x16x32, fp32 acc.
// attn: qkv via MFMA (per-wave, per-block), attention core on VALU.
// stats3 fused into conv3 epilogue (partials + reducer).

#define EPSV 1e-5f
#define INV_N (1.0f / 131072.0f)

typedef unsigned short u16;
typedef __attribute__((ext_vector_type(8))) short short8b;  // 8 bf16
typedef __attribute__((ext_vector_type(4))) float f32x4;

__device__ __forceinline__ u16 f2bf(float f) {
  unsigned u = __float_as_uint(f);
  u += 0x7fffu + ((u >> 16) & 1u);
  return (u16)(u >> 16);
}
__device__ __forceinline__ float bf2f(u16 h) {
  return __uint_as_float((unsigned)h << 16);
}

__device__ __forceinline__ float bn_scale(const float* __restrict__ acc,
                                          const float* __restrict__ gam,
                                          const float* __restrict__ bet,
                                          int C, int c, float& shift) {
  float S = acc[c], S2 = acc[C + c];
  float mean = S * INV_N;
  float var  = S2 * INV_N - mean * mean;
  float rstd = rsqrtf(var + EPSV);
  float sc = gam[c] * rstd;
  shift = bet[c] - mean * sc;
  return sc;
}

// ---------- prep: conv weights -> bf16 chunked [18][O][40]; qkv weights -> [oc 192][c 64] ----------
__global__ __launch_bounds__(256) void prep_kernel(const float* __restrict__ w1,
                                                   const float* __restrict__ w3,
                                                   const float* __restrict__ wq,
                                                   const float* __restrict__ wk,
                                                   const float* __restrict__ wv,
                                                   u16* __restrict__ wp1,
                                                   u16* __restrict__ wp3,
                                                   u16* __restrict__ wqkvT) {
  int i = blockIdx.x * 256 + threadIdx.x;
  const int tot1 = 18 * 64 * 40;
  const int tot3 = 18 * 256 * 40;
  if (i < tot1) {
    int ch = i / (64 * 40); int r = i - ch * 64 * 40; int o = r / 40; int kk = r - o * 40;
    float v = 0.f;
    if (kk < 32) { int k = ch * 32 + kk; int tap = k >> 6; int c = k & 63;
                   v = w1[o * 576 + c * 9 + tap]; }
    wp1[i] = f2bf(v);
  } else if (i < tot1 + tot3) {
    int j = i - tot1;
    int ch = j / (256 * 40); int r = j - ch * 256 * 40; int o = r / 40; int kk = r - o * 40;
    float v = 0.f;
    if (kk < 32) { int k = ch * 32 + kk; int tap = k >> 6; int c = k & 63;
                   v = w3[o * 576 + c * 9 + tap]; }
    wp3[j] = f2bf(v);
  } else if (i < tot1 + tot3 + 192 * 64) {
    int j = i - tot1 - tot3;
    int oc = j >> 6, c = j & 63;
    const float* src = (oc < 64) ? wq : (oc < 128) ? wk : wv;
    wqkvT[j] = f2bf(src[(c << 6) + (oc & 63)]);
  }
}

// ---------- conv1: x (NCHW blocks, fp32) -> buf (NHWC, fp32). M=rows(256), N=o(64) ----------
__global__ __launch_bounds__(256) void conv1_kernel(const float* __restrict__ x,
                                                    const u16* __restrict__ wp,
                                                    float* __restrict__ buf) {
  __shared__ char featA[257 * 128];       // bf16 [row][64ch], XOR-swizzled; row 256 = zeros
  __shared__ char ldsW[2][64 * 80];       // [o][40 bf16] per 32-k chunk
  const int t = threadIdx.x;
  const int lane = t & 63, w = t >> 6;
  const int lrow = lane & 15, lk = lane >> 4;
  const int wm = w >> 1, wn = w & 1;      // wave tile: 128 rows x 32 o
  const size_t Mbase = (size_t)blockIdx.x * 256;

  int rel[9];
  {
    const int pi = lrow >> 2, pj = lrow & 3;
#pragma unroll
    for (int tap = 0; tap < 9; ++tap) {
      const int ti = tap / 3, tj = tap - ti * 3;
      int si = pi + ti - 1, sj = pj + tj - 1;
      bool valid = ((unsigned)si < 4u) && ((unsigned)sj < 4u);
      rel[tap] = valid ? ((si * 4 + sj) << 7) : (1 << 24);
    }
  }

#pragma unroll
  for (int i = 0; i < 16; ++i) {
    float4 v = *reinterpret_cast<const float4*>(x + Mbase * 64 + i * 1024 + t * 4);
    const int c = t >> 2, p0 = (t & 3) * 4;
    float vv[4] = {v.x, v.y, v.z, v.w};
#pragma unroll
    for (int j = 0; j < 4; ++j) {
      int row = i * 16 + p0 + j;
      int byte = row * 128 + ((((c >> 3) ^ (row & 7)) << 4) | ((c & 7) << 1));
      *reinterpret_cast<u16*>(featA + byte) = f2bf(vv[j]);
    }
  }
  if (t < 8) *reinterpret_cast<uint4*>(featA + 256 * 128 + t * 16) = uint4{0, 0, 0, 0};

  uint4 s0, s1;
  {
    const u16* sp = wp;
    s0 = *reinterpret_cast<const uint4*>(sp + (size_t)t * 8);
    if (t < 64) s1 = *reinterpret_cast<const uint4*>(sp + (size_t)(t + 256) * 8);
    *reinterpret_cast<uint4*>(ldsW[0] + t * 16) = s0;
    if (t < 64) *reinterpret_cast<uint4*>(ldsW[0] + (t + 256) * 16) = s1;
  }
  __syncthreads();

  f32x4 acc[8][2] = {};
#pragma unroll
  for (int chn = 0; chn < 18; ++chn) {
    const int cur = chn & 1;
    const int tap = chn >> 1, kk = chn & 1;
    if (chn + 1 < 18) {
      const u16* sp = wp + (chn + 1) * 2560;
      s0 = *reinterpret_cast<const uint4*>(sp + (size_t)t * 8);
      if (t < 64) s1 = *reinterpret_cast<const uint4*>(sp + (size_t)(t + 256) * 8);
    }
    const int kkg = (kk << 6) | (lk << 4);
    short8b bw[2];
#pragma unroll
    for (int n = 0; n < 2; ++n)
      bw[n] = *reinterpret_cast<const short8b*>(ldsW[cur] + (wn * 32 + n * 16 + lrow) * 80 + lk * 16);
#pragma unroll
    for (int m = 0; m < 8; ++m) {
      int ad = ((wm * 128 + m * 16) << 7) + rel[tap];
      ad = ad < 32768 ? ad : 32768;
      ad += (kkg ^ ((ad >> 3) & 0x70));
      short8b af = *reinterpret_cast<const short8b*>(featA + ad);
#pragma unroll
      for (int n = 0; n < 2; ++n)
        acc[m][n] = __builtin_amdgcn_mfma_f32_16x16x32_bf16(af, bw[n], acc[m][n], 0, 0, 0);
    }
    if (chn + 1 < 18) {
      *reinterpret_cast<uint4*>(ldsW[cur ^ 1] + t * 16) = s0;
      if (t < 64) *reinterpret_cast<uint4*>(ldsW[cur ^ 1] + (t + 256) * 16) = s1;
    }
    __syncthreads();
  }

#pragma unroll
  for (int m = 0; m < 8; ++m) {
    const size_t rowg0 = Mbase + wm * 128 + m * 16 + lk * 4;
#pragma unroll
    for (int n = 0; n < 2; ++n) {
      const int o = wn * 32 + n * 16 + lrow;
#pragma unroll
      for (int r = 0; r < 4; ++r)
        buf[(rowg0 + r) * 64 + o] = acc[m][n][r];
    }
  }
}

// ---------- per-channel stats on NHWC buf (C=64): raw S, S2 ----------
__global__ __launch_bounds__(256) void stats_nhwc(const float* __restrict__ src,
                                                  float* __restrict__ acc) {
  const int t = threadIdx.x;
  const int cq = t & 15, ro = t >> 4;
  const size_t base = (size_t)blockIdx.x * 512 + ro;
  float4 s = {0, 0, 0, 0}, s2 = {0, 0, 0, 0};
  for (int i = 0; i < 32; ++i) {
    float4 v = *reinterpret_cast<const float4*>(src + (base + (size_t)i * 16) * 64 + cq * 4);
    s.x += v.x; s.y += v.y; s.z += v.z; s.w += v.w;
    s2.x = fmaf(v.x, v.x, s2.x); s2.y = fmaf(v.y, v.y, s2.y);
    s2.z = fmaf(v.z, v.z, s2.z); s2.w = fmaf(v.w, v.w, s2.w);
  }
#pragma unroll
  for (int off = 32; off >= 16; off >>= 1) {
    s.x += __shfl_down(s.x, off); s.y += __shfl_down(s.y, off);
    s.z += __shfl_down(s.z, off); s.w += __shfl_down(s.w, off);
    s2.x += __shfl_down(s2.x, off); s2.y += __shfl_down(s2.y, off);
    s2.z += __shfl_down(s2.z, off); s2.w += __shfl_down(s2.w, off);
  }
  __shared__ float red[4][16][8];
  const int wv = t >> 6, lane = t & 63;
  if (lane < 16) {
    float* r = red[wv][lane];
    r[0] = s.x; r[1] = s.y; r[2] = s.z; r[3] = s.w;
    r[4] = s2.x; r[5] = s2.y; r[6] = s2.z; r[7] = s2.w;
  }
  __syncthreads();
  if (wv == 0 && lane < 16) {
#pragma unroll
    for (int j = 0; j < 4; ++j) {
      float S = red[0][lane][j] + red[1][lane][j] + red[2][lane][j] + red[3][lane][j];
      float S2 = red[0][lane][4 + j] + red[1][lane][4 + j] + red[2][lane][4 + j] + red[3][lane][4 + j];
      atomicAdd(&acc[lane * 4 + j], S);
      atomicAdd(&acc[64 + lane * 4 + j], S2);
    }
  }
}

// ---------- attn: BN1+relu -> qkv (MFMA) -> rel-pos attention -> buf (NHWC, in-place) ----------
// 256 threads = 4 independent waves, each owning one 4x4 block. No cross-wave deps
// except the shared scsh table (one barrier).
#define QSTR 24            // u16 per (pos) row
#define NSTR 400           // u16 per head (16*24 + 16 pad -> n-groups 8 banks apart)
#define KOFF 1600          // k array base (u16)
#define VOFF 3200          // v array base (u16)
#define USTR 4800          // u16 per wave

__global__ __launch_bounds__(256) void attn_kernel(float* __restrict__ buf,
                                                   const u16* __restrict__ wqkvT,
                                                   const float* __restrict__ relw,
                                                   const float* __restrict__ relh,
                                                   const float* __restrict__ acc1,
                                                   const float* __restrict__ g1,
                                                   const float* __restrict__ b1) {
  __shared__ float scsh[64][2];
  __shared__ u16 feat_l[4][16 * 64];       // bf16 [pos][c], granule-swizzled rows
  __shared__ u16 qkv_l[4][USTR];
  const int t = threadIdx.x, u = t >> 6, lane = t & 63;
  const size_t b = (size_t)blockIdx.x * 4 + u;

  if (t < 64) {
    float sh; float sc = bn_scale(acc1, g1, b1, 64, t, sh);
    scsh[t][0] = sc; scsh[t][1] = sh;
  }
  __syncthreads();

  // ---- stage feat (BN1+relu, bf16, swizzled): lane -> (pos, 16-ch quarter) ----
  {
    const int pos = lane >> 2, cq = lane & 3;
    const float* src = buf + b * 1024 + pos * 64 + cq * 16;
    u16 h[16];
#pragma unroll
    for (int j4 = 0; j4 < 4; ++j4) {
      float4 v = *reinterpret_cast<const float4*>(src + j4 * 4);
      float vv[4] = {v.x, v.y, v.z, v.w};
#pragma unroll
      for (int j = 0; j < 4; ++j) {
        const int c = cq * 16 + j4 * 4 + j;
        h[j4 * 4 + j] = f2bf(fmaxf(fmaf(vv[j], scsh[c][0], scsh[c][1]), 0.f));
      }
    }
    short8b p0, p1;
#pragma unroll
    for (int j = 0; j < 8; ++j) { p0[j] = (short)h[j]; p1[j] = (short)h[8 + j]; }
    const int g0 = (cq * 2) ^ (pos & 7), g1g = (cq * 2 + 1) ^ (pos & 7);
    *reinterpret_cast<short8b*>(&feat_l[u][pos * 64 + g0 * 8]) = p0;
    *reinterpret_cast<short8b*>(&feat_l[u][pos * 64 + g1g * 8]) = p1;
  }

  // ---- qkv via MFMA: D[pos][oc] = feat[pos][c] * wT[oc][c], K=64 in 2 chunks ----
  const int dq = lane & 15, lk = lane >> 4;
  short8b afr[2];
#pragma unroll
  for (int ch = 0; ch < 2; ++ch) {
    const int kg = ch * 4 + lk;
    afr[ch] = *reinterpret_cast<const short8b*>(&feat_l[u][dq * 64 + ((kg ^ (dq & 7)) * 8)]);
  }
#pragma unroll
  for (int ct = 0; ct < 12; ++ct) {
    f32x4 d = {0.f, 0.f, 0.f, 0.f};
#pragma unroll
    for (int ch = 0; ch < 2; ++ch) {
      short8b bfr = *reinterpret_cast<const short8b*>(&wqkvT[(ct * 16 + dq) * 64 + ch * 32 + lk * 8]);
      d = __builtin_amdgcn_mfma_f32_16x16x32_bf16(afr[ch], bfr, d, 0, 0, 0);
    }
    u16* dst;
    float scl = 1.f;
    if (ct < 4)      { dst = &qkv_l[u][ct * NSTR];              scl = 0.25f; }
    else if (ct < 8) { dst = &qkv_l[u][KOFF + (ct - 4) * NSTR]; }
    else             { dst = &qkv_l[u][VOFF + (ct - 8) * NSTR]; }
#pragma unroll
    for (int r = 0; r < 4; ++r)
      dst[(lk * 4 + r) * QSTR + dq] = f2bf(d[r] * scl);
  }

  // ---- attention core: thread = (head n=lk, query pos qp=dq) ----
  const int n = lk, qp = dq;
  const int qi = qp >> 2, qj = qp & 3;
  float q_[16];
  {
    const u16* qrow = &qkv_l[u][n * NSTR + qp * QSTR];
    short8b qa = *reinterpret_cast<const short8b*>(&qrow[0]);
    short8b qb = *reinterpret_cast<const short8b*>(&qrow[8]);
#pragma unroll
    for (int j = 0; j < 8; ++j) { q_[j] = bf2f((u16)qa[j]); q_[8 + j] = bf2f((u16)qb[j]); }
  }
  // rel logits: shift the TABLE pointer by (3-qj)/(3-qi) -> register arrays stay static
  float rwq[4], rhq[4];
  {
    const float* rwp = relw + (3 - qj) * 16;
    const float* rhp = relh + (3 - qi) * 16;
#pragma unroll
    for (int m = 0; m < 4; ++m) {
      float a1 = 0.f, a2 = 0.f;
#pragma unroll
      for (int d2 = 0; d2 < 16; ++d2) {
        a1 = fmaf(q_[d2], rwp[m * 16 + d2], a1);
        a2 = fmaf(q_[d2], rhp[m * 16 + d2], a2);
      }
      rwq[m] = a1; rhq[m] = a2;
    }
  }
  float lo[16]; float mx = -1e30f;
  const u16* kb = &qkv_l[u][KOFF + n * NSTR];
#pragma unroll
  for (int kp = 0; kp < 16; ++kp) {
    short8b k0 = *reinterpret_cast<const short8b*>(&kb[kp * QSTR]);
    short8b k1 = *reinterpret_cast<const short8b*>(&kb[kp * QSTR + 8]);
    float s = rwq[kp & 3] + rhq[kp >> 2];
#pragma unroll
    for (int j = 0; j < 8; ++j) {
      s = fmaf(q_[j], bf2f((u16)k0[j]), s);
      s = fmaf(q_[8 + j], bf2f((u16)k1[j]), s);
    }
    lo[kp] = s; mx = fmaxf(mx, s);
  }
  float ssum = 0.f;
#pragma unroll
  for (int kp = 0; kp < 16; ++kp) { float e = __expf(lo[kp] - mx); lo[kp] = e; ssum += e; }
  const float inv = 1.0f / ssum;
  float ov[16];
#pragma unroll
  for (int j = 0; j < 16; ++j) ov[j] = 0.f;
  const u16* vb = &qkv_l[u][VOFF + n * NSTR];
#pragma unroll
  for (int kp = 0; kp < 16; ++kp) {
    short8b v0 = *reinterpret_cast<const short8b*>(&vb[kp * QSTR]);
    short8b v1 = *reinterpret_cast<const short8b*>(&vb[kp * QSTR + 8]);
    const float wgt = lo[kp];
#pragma unroll
    for (int j = 0; j < 8; ++j) {
      ov[j] = fmaf(wgt, bf2f((u16)v0[j]), ov[j]);
      ov[8 + j] = fmaf(wgt, bf2f((u16)v1[j]), ov[8 + j]);
    }
  }
  float* dst = buf + b * 1024 + qp * 64 + (n << 4);
#pragma unroll
  for (int d4 = 0; d4 < 4; ++d4) {
    float4 vv = {ov[4 * d4] * inv, ov[4 * d4 + 1] * inv, ov[4 * d4 + 2] * inv, ov[4 * d4 + 3] * inv};
    *reinterpret_cast<float4*>(dst + 4 * d4) = vv;
  }
}

// ---------- conv3: BN2+relu(buf NHWC) -> d_out NCHW + fused stats3 partials ----------
__global__ __launch_bounds__(256) void conv3_kernel(const float* __restrict__ src,
                                                    const u16* __restrict__ wp,
                                                    const float* __restrict__ acc2,
                                                    const float* __restrict__ g2,
                                                    const float* __restrict__ b2,
                                                    float* __restrict__ out,
                                                    float* __restrict__ partials) {
  __shared__ __align__(16) char featB[129 * 128];  // bf16 [row][64ch] swizzled; row 128 = zeros
  __shared__ char ldsW[2][128 * 80];
  __shared__ float scsh[128];
  const int t = threadIdx.x;
  const int lane = t & 63, w = t >> 6;
  const int lrow = lane & 15, lk = lane >> 4;
  const int wm = w >> 1, wn = w & 1;
  const int Nbase = blockIdx.x * 128;
  const int ohalf = blockIdx.y;

  int rel[9];
  {
    const int pi = lrow >> 2, pj = lrow & 3;
#pragma unroll
    for (int tap = 0; tap < 9; ++tap) {
      const int ti = tap / 3, tj = tap - ti * 3;
      int si = pi + ti - 1, sj = pj + tj - 1;
      bool valid = ((unsigned)si < 4u) && ((unsigned)sj < 4u);
      rel[tap] = valid ? ((si * 4 + sj) << 7) : (1 << 24);
    }
  }

  if (t < 64) {
    float sh; float sc = bn_scale(acc2, g2, b2, 64, t, sh);
    scsh[t * 2] = sc; scsh[t * 2 + 1] = sh;
  }
  __syncthreads();

  {
    const int row = t >> 1, q2 = t & 1;
    const float* p = src + (size_t)(Nbase + row) * 64 + q2 * 32;
#pragma unroll
    for (int gg = 0; gg < 4; ++gg) {
      float4 a = *reinterpret_cast<const float4*>(p + gg * 8);
      float4 bq = *reinterpret_cast<const float4*>(p + gg * 8 + 4);
      const int cb = q2 * 32 + gg * 8;
      union { u16 h[8]; uint4 uu; } pk;
      float va[8] = {a.x, a.y, a.z, a.w, bq.x, bq.y, bq.z, bq.w};
#pragma unroll
      for (int j = 0; j < 8; ++j)
        pk.h[j] = f2bf(fmaxf(fmaf(va[j], scsh[(cb + j) * 2], scsh[(cb + j) * 2 + 1]), 0.f));
      const int g = (q2 * 4 + gg) ^ (row & 7);
      *reinterpret_cast<uint4*>(featB + row * 128 + g * 16) = pk.uu;
    }
  }
  if (t < 8) *reinterpret_cast<uint4*>(featB + 128 * 128 + t * 16) = uint4{0, 0, 0, 0};

  uint4 s0, s1, s2v;
  {
    const u16* sp = wp + (size_t)ohalf * 5120;
    s0 = *reinterpret_cast<const uint4*>(sp + (size_t)t * 8);
    s1 = *reinterpret_cast<const uint4*>(sp + (size_t)(t + 256) * 8);
    if (t < 128) s2v = *reinterpret_cast<const uint4*>(sp + (size_t)(t + 512) * 8);
    *reinterpret_cast<uint4*>(ldsW[0] + t * 16) = s0;
    *reinterpret_cast<uint4*>(ldsW[0] + (t + 256) * 16) = s1;
    if (t < 128) *reinterpret_cast<uint4*>(ldsW[0] + (t + 512) * 16) = s2v;
  }
  __syncthreads();

  f32x4 acc[4][4] = {};
#pragma unroll
  for (int chn = 0; chn < 18; ++chn) {
    const int cur = chn & 1;
    const int tap = chn >> 1, kk = chn & 1;
    if (chn + 1 < 18) {
      const u16* sp = wp + (size_t)(chn + 1) * 10240 + (size_t)ohalf * 5120;
      s0 = *reinterpret_cast<const uint4*>(sp + (size_t)t * 8);
      s1 = *reinterpret_cast<const uint4*>(sp + (size_t)(t + 256) * 8);
      if (t < 128) s2v = *reinterpret_cast<const uint4*>(sp + (size_t)(t + 512) * 8);
    }
    const int kkg = (kk << 6) | (lk << 4);
    short8b aw[4];
#pragma unroll
    for (int m = 0; m < 4; ++m)
      aw[m] = *reinterpret_cast<const short8b*>(ldsW[cur] + (wm * 64 + m * 16 + lrow) * 80 + lk * 16);
    short8b bf[4];
#pragma unroll
    for (int n = 0; n < 4; ++n) {
      int ad = ((wn * 64 + n * 16) << 7) + rel[tap];
      ad = ad < 16384 ? ad : 16384;
      ad += (kkg ^ ((ad >> 3) & 0x70));
      bf[n] = *reinterpret_cast<const short8b*>(featB + ad);
    }
#pragma unroll
    for (int m = 0; m < 4; ++m)
#pragma unroll
      for (int n = 0; n < 4; ++n)
        acc[m][n] = __builtin_amdgcn_mfma_f32_16x16x32_bf16(aw[m], bf[n], acc[m][n], 0, 0, 0);
    if (chn + 1 < 18) {
      *reinterpret_cast<uint4*>(ldsW[cur ^ 1] + t * 16) = s0;
      *reinterpret_cast<uint4*>(ldsW[cur ^ 1] + (t + 256) * 16) = s1;
      if (t < 128) *reinterpret_cast<uint4*>(ldsW[cur ^ 1] + (t + 512) * 16) = s2v;
    }
    __syncthreads();
  }

  // main output stores
#pragma unroll
  for (int m = 0; m < 4; ++m) {
    const int o = ohalf * 128 + wm * 64 + m * 16 + lk * 4;
#pragma unroll
    for (int n = 0; n < 4; ++n) {
      const int colg = Nbase + wn * 64 + n * 16 + lrow;
      const int b = colg >> 4, p = colg & 15;
      float* dst = out + (size_t)b * 4096 + p;
#pragma unroll
      for (int r = 0; r < 4; ++r)
        dst[(o + r) * 16] = acc[m][n][r];
    }
  }

  // ---- fused stats3: per-WG per-channel partials (reuse featB as scratch) ----
  float* pst = reinterpret_cast<float*>(featB);    // 256 floats
  pst[t] = 0.f;
  __syncthreads();
#pragma unroll
  for (int m = 0; m < 4; ++m) {
#pragma unroll
    for (int r = 0; r < 4; ++r) {
      float s = acc[m][0][r] + acc[m][1][r] + acc[m][2][r] + acc[m][3][r];
      float s2 = acc[m][0][r] * acc[m][0][r] + acc[m][1][r] * acc[m][1][r]
               + acc[m][2][r] * acc[m][2][r] + acc[m][3][r] * acc[m][3][r];
#pragma unroll
      for (int st = 1; st <= 8; st <<= 1) {
        s += __shfl_xor(s, st);
        s2 += __shfl_xor(s2, st);
      }
      if (lrow == 0) {
        const int ch = wm * 64 + m * 16 + lk * 4 + r;
        atomicAdd(&pst[ch * 2], s);
        atomicAdd(&pst[ch * 2 + 1], s2);
      }
    }
  }
  __syncthreads();
  partials[((size_t)(ohalf * 1024 + blockIdx.x)) * 256 + t] = pst[t];
}

// ---------- reduce conv3 partials -> acc3 (raw S, S2 per channel) ----------
__global__ __launch_bounds__(256) void reduce3_kernel(const float* __restrict__ partials,
                                                      float* __restrict__ acc3) {
  const int c = blockIdx.x, t = threadIdx.x;
  const int oh = c >> 7, chl = c & 127;
  float s = 0.f, s2 = 0.f;
  for (int i = t; i < 1024; i += 256) {
    const float* p = partials + ((size_t)(oh * 1024 + i)) * 256 + chl * 2;
    s += p[0]; s2 += p[1];
  }
#pragma unroll
  for (int off = 32; off > 0; off >>= 1) { s += __shfl_down(s, off); s2 += __shfl_down(s2, off); }
  __shared__ float red[8];
  const int wv = t >> 6;
  if ((t & 63) == 0) { red[wv] = s; red[4 + wv] = s2; }
  __syncthreads();
  if (t == 0) {
    acc3[c] = red[0] + red[1] + red[2] + red[3];
    acc3[256 + c] = red[4] + red[5] + red[6] + red[7];
  }
}

// ---------- BN3 + relu in-place on d_out ----------
__global__ __launch_bounds__(256) void final_kernel(float* __restrict__ out,
                                                    const float* __restrict__ acc3,
                                                    const float* __restrict__ g3,
                                                    const float* __restrict__ b3) {
  const size_t i = ((size_t)blockIdx.x * 256 + threadIdx.x) * 4;
  const int c = (int)((i >> 4) & 255);
  float sh; const float sc = bn_scale(acc3, g3, b3, 256, c, sh);
  float4 v = *reinterpret_cast<float4*>(out + i);
  v.x = fmaxf(fmaf(v.x, sc, sh), 0.f);
  v.y = fmaxf(fmaf(v.y, sc, sh), 0.f);
  v.z = fmaxf(fmaf(v.z, sc, sh), 0.f);
  v.w = fmaxf(fmaf(v.w, sc, sh), 0.f);
  *reinterpret_cast<float4*>(out + i) = v;
}

extern "C" void kernel_launch(void* const* d_in, const int* in_sizes, int n_in,
                              void* d_out, int out_size, void* d_ws, size_t ws_size,
                              hipStream_t stream) {
  const float* x   = (const float*)d_in[0];
  const float* w1  = (const float*)d_in[1];
  const float* g1  = (const float*)d_in[3];
  const float* bb1 = (const float*)d_in[4];
  const float* wq  = (const float*)d_in[5];
  const float* wk  = (const float*)d_in[6];
  const float* wv  = (const float*)d_in[7];
  const float* rw  = (const float*)d_in[8];
  const float* rh  = (const float*)d_in[9];
  const float* g2  = (const float*)d_in[10];
  const float* bb2 = (const float*)d_in[11];
  const float* w3  = (const float*)d_in[12];
  const float* g3  = (const float*)d_in[14];
  const float* bb3 = (const float*)d_in[15];
  float* out = (float*)d_out;
  float* ws  = (float*)d_ws;

  float* buf    = ws;                                 // 8388608 floats
  u16*   wp1    = (u16*)(ws + 8388608);               // 46080 u16
  u16*   wp3    = wp1 + 46080;                        // 184320 u16
  u16*   wqkvT  = wp3 + 184320;                       // 12288 u16
  float* acc1   = ws + 8388608 + (46080 + 184320 + 12288 + 0) / 2;   // 121344 u16 = 60672 floats
  float* acc2   = acc1 + 128;
  float* acc3   = acc2 + 128;                         // 512
  float* partials = acc3 + 512;                       // 524288 floats

  hipMemsetAsync(acc1, 0, 256 * sizeof(float), stream);
  prep_kernel<<<949, 256, 0, stream>>>(w1, w3, wq, wk, wv, wp1, wp3, wqkvT);
  conv1_kernel<<<512, 256, 0, stream>>>(x, wp1, buf);
  stats_nhwc<<<256, 256, 0, stream>>>(buf, acc1);
  attn_kernel<<<2048, 256, 0, stream>>>(buf, wqkvT, rw, rh, acc1, g1, bb1);
  stats_nhwc<<<256, 256, 0, stream>>>(buf, acc2);
  conv3_kernel<<<dim3(1024, 2), 256, 0, stream>>>(buf, wp3, acc2, g2, bb2, out, partials);
  reduce3_kernel<<<256, 256, 0, stream>>>(partials, acc3);
  final_kernel<<<32768, 256, 0, stream>>>(out, acc3, g3, bb3);
}

// Round 4
// 172.641 us; speedup vs baseline: 6.7283x; 1.4670x over previous
//
#include <hip/hip_runtime.h>
#include <stdint.h>

// BotBlock pipeline, MFMA version (round 4).
// Block space: 8192 independent 4x4x64 blocks (raw-reshape semantics).
// buf (ws) is bf16 NHWC in block space: buf[row*64 + c], row = b*16 + p.
// d_out NCHW block space: out[b*4096 + o*16 + p].
// Convs = im2col GEMMs, K = 576 (9 taps x 64 ch), bf16 MFMA 16x16x32, fp32 acc.
// All three BN stats fused into producer epilogues (partials + tiny reduce).

#define EPSV 1e-5f
#define INV_N (1.0f / 131072.0f)

typedef unsigned short u16;
typedef __attribute__((ext_vector_type(8))) short short8b;  // 8 bf16
typedef __attribute__((ext_vector_type(4))) float f32x4;

__device__ __forceinline__ u16 f2bf(float f) {
  unsigned u = __float_as_uint(f);
  u += 0x7fffu + ((u >> 16) & 1u);
  return (u16)(u >> 16);
}
__device__ __forceinline__ float bf2f(u16 h) {
  return __uint_as_float((unsigned)h << 16);
}

__device__ __forceinline__ float bn_scale(const float* __restrict__ acc,
                                          const float* __restrict__ gam,
                                          const float* __restrict__ bet,
                                          int C, int c, float& shift) {
  float S = acc[c], S2 = acc[C + c];
  float mean = S * INV_N;
  float var  = S2 * INV_N - mean * mean;
  float rstd = rsqrtf(var + EPSV);
  float sc = gam[c] * rstd;
  shift = bet[c] - mean * sc;
  return sc;
}

// ---------- prep: conv1 w -> [18][64][40]; conv3 w -> [9 tap][256 o][64 c]; qkv -> [192][64] ----------
__global__ __launch_bounds__(256) void prep_kernel(const float* __restrict__ w1,
                                                   const float* __restrict__ w3,
                                                   const float* __restrict__ wq,
                                                   const float* __restrict__ wk,
                                                   const float* __restrict__ wv,
                                                   u16* __restrict__ wp1,
                                                   u16* __restrict__ wp3,
                                                   u16* __restrict__ wqkvT) {
  int i = blockIdx.x * 256 + threadIdx.x;
  const int tot1 = 18 * 64 * 40;       // 46080
  const int tot3 = 9 * 256 * 64;       // 147456
  if (i < tot1) {
    int ch = i / (64 * 40); int r = i - ch * 64 * 40; int o = r / 40; int kk = r - o * 40;
    float v = 0.f;
    if (kk < 32) { int k = ch * 32 + kk; int tap = k >> 6; int c = k & 63;
                   v = w1[o * 576 + c * 9 + tap]; }
    wp1[i] = f2bf(v);
  } else if (i < tot1 + tot3) {
    int j = i - tot1;
    int tap = j >> 14; int r = j & 16383; int o = r >> 6; int c = r & 63;
    wp3[j] = f2bf(w3[o * 576 + c * 9 + tap]);
  } else if (i < tot1 + tot3 + 192 * 64) {
    int j = i - tot1 - tot3;
    int oc = j >> 6, c = j & 63;
    const float* src = (oc < 64) ? wq : (oc < 128) ? wk : wv;
    wqkvT[j] = f2bf(src[(c << 6) + (oc & 63)]);
  }
}

// ---------- conv1: x (NCHW blocks, fp32) -> buf (NHWC bf16) + fused stats1 ----------
__global__ __launch_bounds__(256) void conv1_kernel(const float* __restrict__ x,
                                                    const u16* __restrict__ wp,
                                                    u16* __restrict__ bufb,
                                                    float* __restrict__ partials1) {
  __shared__ __align__(16) char featA[257 * 128];   // bf16 [row][64ch], swizzled; row 256 = zeros
  __shared__ __align__(16) char ldsW[2][64 * 80];   // [o][40 bf16] per 32-k chunk
  const int t = threadIdx.x;
  const int lane = t & 63, w = t >> 6;
  const int lrow = lane & 15, lk = lane >> 4;
  const int wm = w >> 1, wn = w & 1;                // wave tile: 128 rows x 32 o
  const size_t Mbase = (size_t)blockIdx.x * 256;

  int rel[9];
  {
    const int pi = lrow >> 2, pj = lrow & 3;
#pragma unroll
    for (int tap = 0; tap < 9; ++tap) {
      const int ti = tap / 3, tj = tap - ti * 3;
      int si = pi + ti - 1, sj = pj + tj - 1;
      bool valid = ((unsigned)si < 4u) && ((unsigned)sj < 4u);
      rel[tap] = valid ? ((si * 4 + sj) << 7) : (1 << 24);
    }
  }

#pragma unroll
  for (int i = 0; i < 16; ++i) {
    float4 v = *reinterpret_cast<const float4*>(x + Mbase * 64 + i * 1024 + t * 4);
    const int c = t >> 2, p0 = (t & 3) * 4;
    float vv[4] = {v.x, v.y, v.z, v.w};
#pragma unroll
    for (int j = 0; j < 4; ++j) {
      int row = i * 16 + p0 + j;
      int byte = row * 128 + ((((c >> 3) ^ (row & 7)) << 4) | ((c & 7) << 1));
      *reinterpret_cast<u16*>(featA + byte) = f2bf(vv[j]);
    }
  }
  if (t < 8) *reinterpret_cast<uint4*>(featA + 256 * 128 + t * 16) = uint4{0, 0, 0, 0};

  uint4 s0, s1;
  {
    const u16* sp = wp;
    s0 = *reinterpret_cast<const uint4*>(sp + (size_t)t * 8);
    if (t < 64) s1 = *reinterpret_cast<const uint4*>(sp + (size_t)(t + 256) * 8);
    *reinterpret_cast<uint4*>(ldsW[0] + t * 16) = s0;
    if (t < 64) *reinterpret_cast<uint4*>(ldsW[0] + (t + 256) * 16) = s1;
  }
  __syncthreads();

  f32x4 acc[8][2] = {};
#pragma unroll
  for (int chn = 0; chn < 18; ++chn) {
    const int cur = chn & 1;
    const int tap = chn >> 1, kk = chn & 1;
    if (chn + 1 < 18) {
      const u16* sp = wp + (chn + 1) * 2560;
      s0 = *reinterpret_cast<const uint4*>(sp + (size_t)t * 8);
      if (t < 64) s1 = *reinterpret_cast<const uint4*>(sp + (size_t)(t + 256) * 8);
    }
    const int kkg = (kk << 6) | (lk << 4);
    short8b bw[2];
#pragma unroll
    for (int n = 0; n < 2; ++n)
      bw[n] = *reinterpret_cast<const short8b*>(ldsW[cur] + (wn * 32 + n * 16 + lrow) * 80 + lk * 16);
#pragma unroll
    for (int m = 0; m < 8; ++m) {
      int ad = ((wm * 128 + m * 16) << 7) + rel[tap];
      ad = ad < 32768 ? ad : 32768;
      ad += (kkg ^ ((ad >> 3) & 0x70));
      short8b af = *reinterpret_cast<const short8b*>(featA + ad);
#pragma unroll
      for (int n = 0; n < 2; ++n)
        acc[m][n] = __builtin_amdgcn_mfma_f32_16x16x32_bf16(af, bw[n], acc[m][n], 0, 0, 0);
    }
    if (chn + 1 < 18) {
      *reinterpret_cast<uint4*>(ldsW[cur ^ 1] + t * 16) = s0;
      if (t < 64) *reinterpret_cast<uint4*>(ldsW[cur ^ 1] + (t + 256) * 16) = s1;
    }
    __syncthreads();
  }

  // bf16 NHWC stores
#pragma unroll
  for (int m = 0; m < 8; ++m) {
    const size_t rowg0 = Mbase + wm * 128 + m * 16 + lk * 4;
#pragma unroll
    for (int n = 0; n < 2; ++n) {
      const int o = wn * 32 + n * 16 + lrow;
#pragma unroll
      for (int r = 0; r < 4; ++r)
        bufb[(rowg0 + r) * 64 + o] = f2bf(acc[m][n][r]);
    }
  }

  // fused stats1 (channel = o)
  float* pst = reinterpret_cast<float*>(featA);    // [S 64][S2 64]
  if (t < 128) pst[t] = 0.f;
  __syncthreads();
#pragma unroll
  for (int n = 0; n < 2; ++n) {
    float s = 0.f, s2 = 0.f;
#pragma unroll
    for (int m = 0; m < 8; ++m)
#pragma unroll
      for (int r = 0; r < 4; ++r) {
        float v = acc[m][n][r];
        s += v; s2 = fmaf(v, v, s2);
      }
    s += __shfl_xor(s, 16); s2 += __shfl_xor(s2, 16);
    s += __shfl_xor(s, 32); s2 += __shfl_xor(s2, 32);
    if (lk == 0) {
      const int o = wn * 32 + n * 16 + lrow;
      atomicAdd(&pst[o], s);
      atomicAdd(&pst[64 + o], s2);
    }
  }
  __syncthreads();
  if (t < 128) partials1[(size_t)blockIdx.x * 128 + t] = pst[t];
}

// ---------- generic partial reduce for stats1/stats2 (stride 128) ----------
__global__ __launch_bounds__(256) void reduce12_kernel(const float* __restrict__ p,
                                                       float* __restrict__ acc, int nrows) {
  const int c = blockIdx.x, t = threadIdx.x;
  float s = 0.f;
  for (int i = t; i < nrows; i += 256) s += p[(size_t)i * 128 + c];
#pragma unroll
  for (int off = 32; off > 0; off >>= 1) s += __shfl_down(s, off);
  __shared__ float red[4];
  if ((t & 63) == 0) red[t >> 6] = s;
  __syncthreads();
  if (t == 0) acc[c] = red[0] + red[1] + red[2] + red[3];
}

// ---------- attn: BN1+relu -> qkv (MFMA) -> rel-pos attn -> buf bf16 + fused stats2 ----------
#define QSTR 24
#define NSTR 400
#define KOFF 1600
#define VOFF 3200
#define USTR 4800

__global__ __launch_bounds__(256) void attn_kernel(u16* __restrict__ buf,
                                                   const u16* __restrict__ wqkvT,
                                                   const float* __restrict__ relw,
                                                   const float* __restrict__ relh,
                                                   const float* __restrict__ acc1,
                                                   const float* __restrict__ g1,
                                                   const float* __restrict__ b1,
                                                   float* __restrict__ partials2) {
  __shared__ float scsh[64][2];
  __shared__ float pstA[128];
  __shared__ __align__(16) u16 feat_l[4][16 * 64];
  __shared__ __align__(16) u16 qkv_l[4][USTR];
  const int t = threadIdx.x, u = t >> 6, lane = t & 63;
  const size_t b = (size_t)blockIdx.x * 4 + u;

  if (t < 64) {
    float sh; float sc = bn_scale(acc1, g1, b1, 64, t, sh);
    scsh[t][0] = sc; scsh[t][1] = sh;
  }
  if (t < 128) pstA[t] = 0.f;
  __syncthreads();

  // ---- stage feat (BN1+relu on bf16 buf): lane -> (pos, 16-ch quarter) ----
  {
    const int pos = lane >> 2, cq = lane & 3;
    const u16* src = buf + b * 1024 + pos * 64 + cq * 16;
    short8b v0 = *reinterpret_cast<const short8b*>(src);
    short8b v1 = *reinterpret_cast<const short8b*>(src + 8);
    short8b p0, p1;
#pragma unroll
    for (int j = 0; j < 8; ++j) {
      const int c0 = cq * 16 + j, c1 = cq * 16 + 8 + j;
      p0[j] = (short)f2bf(fmaxf(fmaf(bf2f((u16)v0[j]), scsh[c0][0], scsh[c0][1]), 0.f));
      p1[j] = (short)f2bf(fmaxf(fmaf(bf2f((u16)v1[j]), scsh[c1][0], scsh[c1][1]), 0.f));
    }
    const int g0 = (cq * 2) ^ (pos & 7), g1g = (cq * 2 + 1) ^ (pos & 7);
    *reinterpret_cast<short8b*>(&feat_l[u][pos * 64 + g0 * 8]) = p0;
    *reinterpret_cast<short8b*>(&feat_l[u][pos * 64 + g1g * 8]) = p1;
  }

  // ---- qkv via MFMA ----
  const int dq = lane & 15, lk = lane >> 4;
  short8b afr[2];
#pragma unroll
  for (int ch = 0; ch < 2; ++ch) {
    const int kg = ch * 4 + lk;
    afr[ch] = *reinterpret_cast<const short8b*>(&feat_l[u][dq * 64 + ((kg ^ (dq & 7)) * 8)]);
  }
#pragma unroll
  for (int ct = 0; ct < 12; ++ct) {
    f32x4 d = {0.f, 0.f, 0.f, 0.f};
#pragma unroll
    for (int ch = 0; ch < 2; ++ch) {
      short8b bfr = *reinterpret_cast<const short8b*>(&wqkvT[(ct * 16 + dq) * 64 + ch * 32 + lk * 8]);
      d = __builtin_amdgcn_mfma_f32_16x16x32_bf16(afr[ch], bfr, d, 0, 0, 0);
    }
    u16* dst;
    float scl = 1.f;
    if (ct < 4)      { dst = &qkv_l[u][ct * NSTR];              scl = 0.25f; }
    else if (ct < 8) { dst = &qkv_l[u][KOFF + (ct - 4) * NSTR]; }
    else             { dst = &qkv_l[u][VOFF + (ct - 8) * NSTR]; }
#pragma unroll
    for (int r = 0; r < 4; ++r)
      dst[(lk * 4 + r) * QSTR + dq] = f2bf(d[r] * scl);
  }

  // ---- attention core: thread = (head n=lk, query pos qp=dq) ----
  const int n = lk, qp = dq;
  const int qi = qp >> 2, qj = qp & 3;
  float q_[16];
  {
    const u16* qrow = &qkv_l[u][n * NSTR + qp * QSTR];
    short8b qa = *reinterpret_cast<const short8b*>(&qrow[0]);
    short8b qb = *reinterpret_cast<const short8b*>(&qrow[8]);
#pragma unroll
    for (int j = 0; j < 8; ++j) { q_[j] = bf2f((u16)qa[j]); q_[8 + j] = bf2f((u16)qb[j]); }
  }
  float rwq[4], rhq[4];
  {
    const float* rwp = relw + (3 - qj) * 16;
    const float* rhp = relh + (3 - qi) * 16;
#pragma unroll
    for (int m = 0; m < 4; ++m) {
      float a1 = 0.f, a2 = 0.f;
#pragma unroll
      for (int d2 = 0; d2 < 16; ++d2) {
        a1 = fmaf(q_[d2], rwp[m * 16 + d2], a1);
        a2 = fmaf(q_[d2], rhp[m * 16 + d2], a2);
      }
      rwq[m] = a1; rhq[m] = a2;
    }
  }
  float lo[16]; float mx = -1e30f;
  const u16* kb = &qkv_l[u][KOFF + n * NSTR];
#pragma unroll
  for (int kp = 0; kp < 16; ++kp) {
    short8b k0 = *reinterpret_cast<const short8b*>(&kb[kp * QSTR]);
    short8b k1 = *reinterpret_cast<const short8b*>(&kb[kp * QSTR + 8]);
    float s = rwq[kp & 3] + rhq[kp >> 2];
#pragma unroll
    for (int j = 0; j < 8; ++j) {
      s = fmaf(q_[j], bf2f((u16)k0[j]), s);
      s = fmaf(q_[8 + j], bf2f((u16)k1[j]), s);
    }
    lo[kp] = s; mx = fmaxf(mx, s);
  }
  float ssum = 0.f;
#pragma unroll
  for (int kp = 0; kp < 16; ++kp) { float e = __expf(lo[kp] - mx); lo[kp] = e; ssum += e; }
  const float inv = 1.0f / ssum;
  float ov[16];
#pragma unroll
  for (int j = 0; j < 16; ++j) ov[j] = 0.f;
  const u16* vb = &qkv_l[u][VOFF + n * NSTR];
#pragma unroll
  for (int kp = 0; kp < 16; ++kp) {
    short8b v0 = *reinterpret_cast<const short8b*>(&vb[kp * QSTR]);
    short8b v1 = *reinterpret_cast<const short8b*>(&vb[kp * QSTR + 8]);
    const float wgt = lo[kp];
#pragma unroll
    for (int j = 0; j < 8; ++j) {
      ov[j] = fmaf(wgt, bf2f((u16)v0[j]), ov[j]);
      ov[8 + j] = fmaf(wgt, bf2f((u16)v1[j]), ov[8 + j]);
    }
  }
#pragma unroll
  for (int j = 0; j < 16; ++j) ov[j] *= inv;

  // bf16 output write
  {
    short8b o0, o1;
#pragma unroll
    for (int j = 0; j < 8; ++j) {
      o0[j] = (short)f2bf(ov[j]);
      o1[j] = (short)f2bf(ov[8 + j]);
    }
    u16* dstb = buf + b * 1024 + qp * 64 + (n << 4);
    *reinterpret_cast<short8b*>(dstb) = o0;
    *reinterpret_cast<short8b*>(dstb + 8) = o1;
  }

  // ---- fused stats2: per-wave LDS transpose (reuse qkv_l), column sums ----
  {
    float* fl = reinterpret_cast<float*>(&qkv_l[u][0]);   // [16 pos][69]
#pragma unroll
    for (int j = 0; j < 16; ++j) fl[qp * 69 + n * 16 + j] = ov[j];
    const int c = lane;                                   // 0..63 channel
    float s = 0.f, s2 = 0.f;
#pragma unroll
    for (int pos = 0; pos < 16; ++pos) {
      float v = fl[pos * 69 + c];
      s += v; s2 = fmaf(v, v, s2);
    }
    atomicAdd(&pstA[c], s);
    atomicAdd(&pstA[64 + c], s2);
  }
  __syncthreads();
  if (t < 128) partials2[(size_t)blockIdx.x * 128 + t] = pstA[t];
}

// ---------- conv3: BN2+relu(buf bf16 NHWC) -> d_out NCHW + fused stats3 ----------
// grid (512, 2): 256 rows per WG, o-half per blockIdx.y. Wave tile 64o x 128pos.
__global__ __launch_bounds__(256, 2) void conv3_kernel(const u16* __restrict__ src,
                                                       const u16* __restrict__ wp,
                                                       const float* __restrict__ acc2,
                                                       const float* __restrict__ g2,
                                                       const float* __restrict__ b2,
                                                       float* __restrict__ out,
                                                       float* __restrict__ partials3) {
  __shared__ __align__(16) u16 featB[257 * 64];     // bf16 [256 rows][64ch] swizzled; row 256 = zeros
  __shared__ __align__(16) u16 ldsW[2][128 * 64];   // [o 128][64 k] per tap, swizzled
  __shared__ float scsh[128];
  const int t = threadIdx.x;
  const int lane = t & 63, w = t >> 6;
  const int lrow = lane & 15, lk = lane >> 4;
  const int wm = w >> 1, wn = w & 1;
  const int Nbase = blockIdx.x * 256;
  const int ohalf = blockIdx.y;

  int rel[9];
  {
    const int pi = lrow >> 2, pj = lrow & 3;
#pragma unroll
    for (int tap = 0; tap < 9; ++tap) {
      const int ti = tap / 3, tj = tap - ti * 3;
      int si = pi + ti - 1, sj = pj + tj - 1;
      bool valid = ((unsigned)si < 4u) && ((unsigned)sj < 4u);
      rel[tap] = valid ? ((si * 4 + sj) << 7) : (1 << 24);
    }
  }

  if (t < 64) {
    float sh; float sc = bn_scale(acc2, g2, b2, 64, t, sh);
    scsh[t * 2] = sc; scsh[t * 2 + 1] = sh;
  }

  // W tap0 -> ldsW[0] (no scsh dependency)
  const int so = t >> 1, shalf = t & 1, so7 = so & 7;
  {
    const u16* wsrc = wp + ohalf * 8192 + so * 64 + shalf * 32;
    uint4 w0 = *reinterpret_cast<const uint4*>(wsrc);
    uint4 w1 = *reinterpret_cast<const uint4*>(wsrc + 8);
    uint4 w2 = *reinterpret_cast<const uint4*>(wsrc + 16);
    uint4 w3v = *reinterpret_cast<const uint4*>(wsrc + 24);
    char* dst = (char*)ldsW[0] + so * 128;
    const int gb = shalf * 4;
    *reinterpret_cast<uint4*>(dst + (((gb + 0) ^ so7) << 4)) = w0;
    *reinterpret_cast<uint4*>(dst + (((gb + 1) ^ so7) << 4)) = w1;
    *reinterpret_cast<uint4*>(dst + (((gb + 2) ^ so7) << 4)) = w2;
    *reinterpret_cast<uint4*>(dst + (((gb + 3) ^ so7) << 4)) = w3v;
  }
  __syncthreads();

  // featB staging (BN2+relu): thread t -> row t
  {
    const u16* srow = src + (size_t)(Nbase + t) * 64;
    char* drow = (char*)featB + t * 128;
    const int r7 = t & 7;
#pragma unroll
    for (int g = 0; g < 8; ++g) {
      short8b v = *reinterpret_cast<const short8b*>(srow + g * 8);
      short8b pk;
#pragma unroll
      for (int j = 0; j < 8; ++j) {
        const int c = g * 8 + j;
        pk[j] = (short)f2bf(fmaxf(fmaf(bf2f((u16)v[j]), scsh[c * 2], scsh[c * 2 + 1]), 0.f));
      }
      *reinterpret_cast<short8b*>(drow + ((g ^ r7) << 4)) = pk;
    }
  }
  if (t < 8) *reinterpret_cast<uint4*>((char*)featB + 32768 + t * 16) = uint4{0, 0, 0, 0};

  // W tap1 -> regs
  uint4 r0, r1, r2, r3v;
  {
    const u16* wsrc = wp + 16384 + ohalf * 8192 + so * 64 + shalf * 32;
    r0 = *reinterpret_cast<const uint4*>(wsrc);
    r1 = *reinterpret_cast<const uint4*>(wsrc + 8);
    r2 = *reinterpret_cast<const uint4*>(wsrc + 16);
    r3v = *reinterpret_cast<const uint4*>(wsrc + 24);
  }
  __syncthreads();

  f32x4 acc[4][8] = {};
  const char* fB = (const char*)featB;
  const int swzA0 = (lk << 4) ^ ((lrow & 7) << 4);
  const int swzA1 = (64 | (lk << 4)) ^ ((lrow & 7) << 4);

#pragma unroll
  for (int tap = 0; tap < 9; ++tap) {
    const int cur = tap & 1;
    const char* lW = (const char*)ldsW[cur];
    short8b aw0[4], aw1[4];
#pragma unroll
    for (int m = 0; m < 4; ++m) {
      const int rowoff = (wm * 64 + m * 16 + lrow) << 7;
      aw0[m] = *reinterpret_cast<const short8b*>(lW + rowoff + swzA0);
      aw1[m] = *reinterpret_cast<const short8b*>(lW + rowoff + swzA1);
    }
#pragma unroll
    for (int n = 0; n < 8; ++n) {
      int ad0 = ((wn * 128 + n * 16) << 7) + rel[tap];
      ad0 = ad0 < 32768 ? ad0 : 32768;
      const int swz = (ad0 >> 3) & 0x70;
      short8b bf0 = *reinterpret_cast<const short8b*>(fB + ad0 + ((lk << 4) ^ swz));
      short8b bf1 = *reinterpret_cast<const short8b*>(fB + ad0 + ((64 | (lk << 4)) ^ swz));
#pragma unroll
      for (int m = 0; m < 4; ++m) {
        acc[m][n] = __builtin_amdgcn_mfma_f32_16x16x32_bf16(aw0[m], bf0, acc[m][n], 0, 0, 0);
        acc[m][n] = __builtin_amdgcn_mfma_f32_16x16x32_bf16(aw1[m], bf1, acc[m][n], 0, 0, 0);
      }
    }
    if (tap < 8) {
      // write W[tap+1] regs -> other buffer
      char* dst = (char*)ldsW[cur ^ 1] + so * 128;
      const int gb = shalf * 4;
      *reinterpret_cast<uint4*>(dst + (((gb + 0) ^ so7) << 4)) = r0;
      *reinterpret_cast<uint4*>(dst + (((gb + 1) ^ so7) << 4)) = r1;
      *reinterpret_cast<uint4*>(dst + (((gb + 2) ^ so7) << 4)) = r2;
      *reinterpret_cast<uint4*>(dst + (((gb + 3) ^ so7) << 4)) = r3v;
      if (tap < 7) {
        const u16* wsrc = wp + (tap + 2) * 16384 + ohalf * 8192 + so * 64 + shalf * 32;
        r0 = *reinterpret_cast<const uint4*>(wsrc);
        r1 = *reinterpret_cast<const uint4*>(wsrc + 8);
        r2 = *reinterpret_cast<const uint4*>(wsrc + 16);
        r3v = *reinterpret_cast<const uint4*>(wsrc + 24);
      }
    }
    __syncthreads();
  }

  // NCHW stores: D[o][pos]
#pragma unroll
  for (int m = 0; m < 4; ++m) {
    const int o = ohalf * 128 + wm * 64 + m * 16 + lk * 4;
#pragma unroll
    for (int n = 0; n < 8; ++n) {
      const int colg = Nbase + wn * 128 + n * 16 + lrow;
      const int b = colg >> 4, p = colg & 15;
      float* dst = out + (size_t)b * 4096 + (size_t)o * 16 + p;
#pragma unroll
      for (int r = 0; r < 4; ++r)
        dst[r * 16] = acc[m][n][r];
    }
  }

  // fused stats3 partials (channel-local to o-half)
  float* pst = reinterpret_cast<float*>(featB);     // [S 128][S2 128]
  pst[t] = 0.f;
  __syncthreads();
#pragma unroll
  for (int m = 0; m < 4; ++m) {
#pragma unroll
    for (int r = 0; r < 4; ++r) {
      float s = 0.f, s2 = 0.f;
#pragma unroll
      for (int n = 0; n < 8; ++n) {
        float v = acc[m][n][r];
        s += v; s2 = fmaf(v, v, s2);
      }
      s += __shfl_xor(s, 1); s2 += __shfl_xor(s2, 1);
      s += __shfl_xor(s, 2); s2 += __shfl_xor(s2, 2);
      s += __shfl_xor(s, 4); s2 += __shfl_xor(s2, 4);
      s += __shfl_xor(s, 8); s2 += __shfl_xor(s2, 8);
      if (lrow == 0) {
        const int ch = wm * 64 + m * 16 + lk * 4 + r;
        atomicAdd(&pst[ch], s);
        atomicAdd(&pst[128 + ch], s2);
      }
    }
  }
  __syncthreads();
  partials3[((size_t)(ohalf * 512 + blockIdx.x)) * 256 + t] = pst[t];
}

// ---------- reduce conv3 partials -> acc3 ([S 256][S2 256]) ----------
__global__ __launch_bounds__(256) void reduce3_kernel(const float* __restrict__ p,
                                                      float* __restrict__ acc3) {
  const int c2 = blockIdx.x, t = threadIdx.x;       // 0..511
  const int kind = c2 >> 8, c = c2 & 255;
  const int h = c >> 7, chl = c & 127;
  float s = 0.f;
  for (int i = t; i < 512; i += 256)
    s += p[((size_t)(h * 512 + i)) * 256 + kind * 128 + chl];
#pragma unroll
  for (int off = 32; off > 0; off >>= 1) s += __shfl_down(s, off);
  __shared__ float red[4];
  if ((t & 63) == 0) red[t >> 6] = s;
  __syncthreads();
  if (t == 0) acc3[kind * 256 + c] = red[0] + red[1] + red[2] + red[3];
}

// ---------- BN3 + relu in-place on d_out ----------
__global__ __launch_bounds__(256) void final_kernel(float* __restrict__ out,
                                                    const float* __restrict__ acc3,
                                                    const float* __restrict__ g3,
                                                    const float* __restrict__ b3) {
  const size_t i = ((size_t)blockIdx.x * 256 + threadIdx.x) * 4;
  const int c = (int)((i >> 4) & 255);
  float sh; const float sc = bn_scale(acc3, g3, b3, 256, c, sh);
  float4 v = *reinterpret_cast<float4*>(out + i);
  v.x = fmaxf(fmaf(v.x, sc, sh), 0.f);
  v.y = fmaxf(fmaf(v.y, sc, sh), 0.f);
  v.z = fmaxf(fmaf(v.z, sc, sh), 0.f);
  v.w = fmaxf(fmaf(v.w, sc, sh), 0.f);
  *reinterpret_cast<float4*>(out + i) = v;
}

extern "C" void kernel_launch(void* const* d_in, const int* in_sizes, int n_in,
                              void* d_out, int out_size, void* d_ws, size_t ws_size,
                              hipStream_t stream) {
  const float* x   = (const float*)d_in[0];
  const float* w1  = (const float*)d_in[1];
  const float* g1  = (const float*)d_in[3];
  const float* bb1 = (const float*)d_in[4];
  const float* wq  = (const float*)d_in[5];
  const float* wk  = (const float*)d_in[6];
  const float* wv  = (const float*)d_in[7];
  const float* rw  = (const float*)d_in[8];
  const float* rh  = (const float*)d_in[9];
  const float* g2  = (const float*)d_in[10];
  const float* bb2 = (const float*)d_in[11];
  const float* w3  = (const float*)d_in[12];
  const float* g3  = (const float*)d_in[14];
  const float* bb3 = (const float*)d_in[15];
  float* out = (float*)d_out;
  float* ws  = (float*)d_ws;

  u16*   bufb   = (u16*)ws;                 // 8388608 u16
  u16*   wp1    = bufb + 8388608;           // 46080
  u16*   wp3    = wp1 + 46080;              // 147456
  u16*   wqkvT  = wp3 + 147456;             // 12288
  float* acc1   = ws + 4297216;             // 128  (u16 total above = 8594432 = 4297216 floats)
  float* acc2   = acc1 + 128;               // 128
  float* acc3   = acc2 + 128;               // 512
  float* part1  = acc3 + 512;               // 512*128   = 65536
  float* part2  = part1 + 65536;            // 2048*128  = 262144
  float* part3  = part2 + 262144;           // 1024*256  = 262144

  prep_kernel<<<804, 256, 0, stream>>>(w1, w3, wq, wk, wv, wp1, wp3, wqkvT);
  conv1_kernel<<<512, 256, 0, stream>>>(x, wp1, bufb, part1);
  reduce12_kernel<<<128, 256, 0, stream>>>(part1, acc1, 512);
  attn_kernel<<<2048, 256, 0, stream>>>(bufb, wqkvT, rw, rh, acc1, g1, bb1, part2);
  reduce12_kernel<<<128, 256, 0, stream>>>(part2, acc2, 2048);
  conv3_kernel<<<dim3(512, 2), 256, 0, stream>>>(bufb, wp3, acc2, g2, bb2, out, part3);
  reduce3_kernel<<<512, 256, 0, stream>>>(part3, acc3);
  final_kernel<<<32768, 256, 0, stream>>>(out, acc3, g3, bb3);
}

// Round 5
// 163.887 us; speedup vs baseline: 7.0877x; 1.0534x over previous
//
#include <hip/hip_runtime.h>
#include <stdint.h>

// BotBlock pipeline, MFMA version (round 5).
// Block space: 8192 independent 4x4x64 blocks (raw-reshape semantics).
// buf (ws) is bf16 NHWC in block space: buf[row*64 + c], row = b*16 + p.
// y3b (ws) is bf16 NCHW pre-BN3 conv3 output; final = BN3+relu bf16->fp32 d_out.
// Convs = im2col GEMMs, K = 576 (9 taps x 64 ch), bf16 MFMA 16x16x32, fp32 acc.
// All three BN stats fused into producer epilogues (partials + tiny reduce).
// attn: qkv via MFMA, f32 LDS for q/k/v (no bf16 decode in hot loops).

#define EPSV 1e-5f
#define INV_N (1.0f / 131072.0f)

typedef unsigned short u16;
typedef __attribute__((ext_vector_type(8))) short short8b;  // 8 bf16
typedef __attribute__((ext_vector_type(4))) float f32x4;

__device__ __forceinline__ u16 f2bf(float f) {
  unsigned u = __float_as_uint(f);
  u += 0x7fffu + ((u >> 16) & 1u);
  return (u16)(u >> 16);
}
__device__ __forceinline__ float bf2f(u16 h) {
  return __uint_as_float((unsigned)h << 16);
}

__device__ __forceinline__ float bn_scale(const float* __restrict__ acc,
                                          const float* __restrict__ gam,
                                          const float* __restrict__ bet,
                                          int C, int c, float& shift) {
  float S = acc[c], S2 = acc[C + c];
  float mean = S * INV_N;
  float var  = S2 * INV_N - mean * mean;
  float rstd = rsqrtf(var + EPSV);
  float sc = gam[c] * rstd;
  shift = bet[c] - mean * sc;
  return sc;
}

// ---------- prep: conv1 w -> [18][64][40]; conv3 w -> [9 tap][256 o][64 c]; qkv -> [192][64] ----------
__global__ __launch_bounds__(256) void prep_kernel(const float* __restrict__ w1,
                                                   const float* __restrict__ w3,
                                                   const float* __restrict__ wq,
                                                   const float* __restrict__ wk,
                                                   const float* __restrict__ wv,
                                                   u16* __restrict__ wp1,
                                                   u16* __restrict__ wp3,
                                                   u16* __restrict__ wqkvT) {
  int i = blockIdx.x * 256 + threadIdx.x;
  const int tot1 = 18 * 64 * 40;       // 46080
  const int tot3 = 9 * 256 * 64;       // 147456
  if (i < tot1) {
    int ch = i / (64 * 40); int r = i - ch * 64 * 40; int o = r / 40; int kk = r - o * 40;
    float v = 0.f;
    if (kk < 32) { int k = ch * 32 + kk; int tap = k >> 6; int c = k & 63;
                   v = w1[o * 576 + c * 9 + tap]; }
    wp1[i] = f2bf(v);
  } else if (i < tot1 + tot3) {
    int j = i - tot1;
    int tap = j >> 14; int r = j & 16383; int o = r >> 6; int c = r & 63;
    wp3[j] = f2bf(w3[o * 576 + c * 9 + tap]);
  } else if (i < tot1 + tot3 + 192 * 64) {
    int j = i - tot1 - tot3;
    int oc = j >> 6, c = j & 63;
    const float* src = (oc < 64) ? wq : (oc < 128) ? wk : wv;
    wqkvT[j] = f2bf(src[(c << 6) + (oc & 63)]);
  }
}

// ---------- conv1: x (NCHW blocks, fp32) -> buf (NHWC bf16) + fused stats1 ----------
__global__ __launch_bounds__(256) void conv1_kernel(const float* __restrict__ x,
                                                    const u16* __restrict__ wp,
                                                    u16* __restrict__ bufb,
                                                    float* __restrict__ partials1) {
  __shared__ __align__(16) char featA[257 * 128];   // bf16 [row][64ch], swizzled; row 256 = zeros
  __shared__ __align__(16) char ldsW[2][64 * 80];   // [o][40 bf16] per 32-k chunk
  const int t = threadIdx.x;
  const int lane = t & 63, w = t >> 6;
  const int lrow = lane & 15, lk = lane >> 4;
  const int wm = w >> 1, wn = w & 1;                // wave tile: 128 rows x 32 o
  const size_t Mbase = (size_t)blockIdx.x * 256;

  int rel[9];
  {
    const int pi = lrow >> 2, pj = lrow & 3;
#pragma unroll
    for (int tap = 0; tap < 9; ++tap) {
      const int ti = tap / 3, tj = tap - ti * 3;
      int si = pi + ti - 1, sj = pj + tj - 1;
      bool valid = ((unsigned)si < 4u) && ((unsigned)sj < 4u);
      rel[tap] = valid ? ((si * 4 + sj) << 7) : (1 << 24);
    }
  }

#pragma unroll
  for (int i = 0; i < 16; ++i) {
    float4 v = *reinterpret_cast<const float4*>(x + Mbase * 64 + i * 1024 + t * 4);
    const int c = t >> 2, p0 = (t & 3) * 4;
    float vv[4] = {v.x, v.y, v.z, v.w};
#pragma unroll
    for (int j = 0; j < 4; ++j) {
      int row = i * 16 + p0 + j;
      int byte = row * 128 + ((((c >> 3) ^ (row & 7)) << 4) | ((c & 7) << 1));
      *reinterpret_cast<u16*>(featA + byte) = f2bf(vv[j]);
    }
  }
  if (t < 8) *reinterpret_cast<uint4*>(featA + 256 * 128 + t * 16) = uint4{0, 0, 0, 0};

  uint4 s0, s1;
  {
    const u16* sp = wp;
    s0 = *reinterpret_cast<const uint4*>(sp + (size_t)t * 8);
    if (t < 64) s1 = *reinterpret_cast<const uint4*>(sp + (size_t)(t + 256) * 8);
    *reinterpret_cast<uint4*>(ldsW[0] + t * 16) = s0;
    if (t < 64) *reinterpret_cast<uint4*>(ldsW[0] + (t + 256) * 16) = s1;
  }
  __syncthreads();

  f32x4 acc[8][2] = {};
#pragma unroll
  for (int chn = 0; chn < 18; ++chn) {
    const int cur = chn & 1;
    const int tap = chn >> 1, kk = chn & 1;
    if (chn + 1 < 18) {
      const u16* sp = wp + (chn + 1) * 2560;
      s0 = *reinterpret_cast<const uint4*>(sp + (size_t)t * 8);
      if (t < 64) s1 = *reinterpret_cast<const uint4*>(sp + (size_t)(t + 256) * 8);
    }
    const int kkg = (kk << 6) | (lk << 4);
    short8b bw[2];
#pragma unroll
    for (int n = 0; n < 2; ++n)
      bw[n] = *reinterpret_cast<const short8b*>(ldsW[cur] + (wn * 32 + n * 16 + lrow) * 80 + lk * 16);
#pragma unroll
    for (int m = 0; m < 8; ++m) {
      int ad = ((wm * 128 + m * 16) << 7) + rel[tap];
      ad = ad < 32768 ? ad : 32768;
      ad += (kkg ^ ((ad >> 3) & 0x70));
      short8b af = *reinterpret_cast<const short8b*>(featA + ad);
#pragma unroll
      for (int n = 0; n < 2; ++n)
        acc[m][n] = __builtin_amdgcn_mfma_f32_16x16x32_bf16(af, bw[n], acc[m][n], 0, 0, 0);
    }
    if (chn + 1 < 18) {
      *reinterpret_cast<uint4*>(ldsW[cur ^ 1] + t * 16) = s0;
      if (t < 64) *reinterpret_cast<uint4*>(ldsW[cur ^ 1] + (t + 256) * 16) = s1;
    }
    __syncthreads();
  }

  // bf16 NHWC stores
#pragma unroll
  for (int m = 0; m < 8; ++m) {
    const size_t rowg0 = Mbase + wm * 128 + m * 16 + lk * 4;
#pragma unroll
    for (int n = 0; n < 2; ++n) {
      const int o = wn * 32 + n * 16 + lrow;
#pragma unroll
      for (int r = 0; r < 4; ++r)
        bufb[(rowg0 + r) * 64 + o] = f2bf(acc[m][n][r]);
    }
  }

  // fused stats1 (channel = o)
  float* pst = reinterpret_cast<float*>(featA);    // [S 64][S2 64]
  if (t < 128) pst[t] = 0.f;
  __syncthreads();
#pragma unroll
  for (int n = 0; n < 2; ++n) {
    float s = 0.f, s2 = 0.f;
#pragma unroll
    for (int m = 0; m < 8; ++m)
#pragma unroll
      for (int r = 0; r < 4; ++r) {
        float v = acc[m][n][r];
        s += v; s2 = fmaf(v, v, s2);
      }
    s += __shfl_xor(s, 16); s2 += __shfl_xor(s2, 16);
    s += __shfl_xor(s, 32); s2 += __shfl_xor(s2, 32);
    if (lk == 0) {
      const int o = wn * 32 + n * 16 + lrow;
      atomicAdd(&pst[o], s);
      atomicAdd(&pst[64 + o], s2);
    }
  }
  __syncthreads();
  if (t < 128) partials1[(size_t)blockIdx.x * 128 + t] = pst[t];
}

// ---------- generic partial reduce for stats1/stats2 (stride 128) ----------
__global__ __launch_bounds__(256) void reduce12_kernel(const float* __restrict__ p,
                                                       float* __restrict__ acc, int nrows) {
  const int c = blockIdx.x, t = threadIdx.x;
  float s = 0.f;
  for (int i = t; i < nrows; i += 256) s += p[(size_t)i * 128 + c];
#pragma unroll
  for (int off = 32; off > 0; off >>= 1) s += __shfl_down(s, off);
  __shared__ float red[4];
  if ((t & 63) == 0) red[t >> 6] = s;
  __syncthreads();
  if (t == 0) acc[c] = red[0] + red[1] + red[2] + red[3];
}

// ---------- attn: BN1+relu -> qkv (MFMA) -> rel-pos attn (f32 LDS) -> buf bf16 + stats2 ----------
// Per-wave f32 LDS layout (floats, base Wf):
//   Q: base 0,    head stride 280, row stride 17 (scalar reads)
//   K: base 1120, head stride 264, row stride 16, col-group XOR by writer-lk
//   V: base 2176, same as K
// stats2 scratch reuses Wf ([16][69]) after PV.
__global__ __launch_bounds__(256) void attn_kernel(u16* __restrict__ buf,
                                                   const u16* __restrict__ wqkvT,
                                                   const float* __restrict__ relw,
                                                   const float* __restrict__ relh,
                                                   const float* __restrict__ acc1,
                                                   const float* __restrict__ g1,
                                                   const float* __restrict__ b1,
                                                   float* __restrict__ partials2) {
  __shared__ float scsh[64][2];
  __shared__ float pstA[128];
  __shared__ __align__(16) u16 feat_l[4][1024];
  __shared__ __align__(16) float qkvf[4][3264];
  const int t = threadIdx.x, u = t >> 6, lane = t & 63;
  const size_t b = (size_t)blockIdx.x * 4 + u;
  float* Wf = qkvf[u];

  if (t < 64) {
    float sh; float sc = bn_scale(acc1, g1, b1, 64, t, sh);
    scsh[t][0] = sc; scsh[t][1] = sh;
  }
  if (t < 128) pstA[t] = 0.f;
  __syncthreads();

  // ---- stage feat (BN1+relu on bf16 buf): lane -> (pos, 16-ch quarter) ----
  {
    const int pos = lane >> 2, cq = lane & 3;
    const u16* src = buf + b * 1024 + pos * 64 + cq * 16;
    short8b v0 = *reinterpret_cast<const short8b*>(src);
    short8b v1 = *reinterpret_cast<const short8b*>(src + 8);
    short8b p0, p1;
#pragma unroll
    for (int j = 0; j < 8; ++j) {
      const int c0 = cq * 16 + j, c1 = cq * 16 + 8 + j;
      p0[j] = (short)f2bf(fmaxf(fmaf(bf2f((u16)v0[j]), scsh[c0][0], scsh[c0][1]), 0.f));
      p1[j] = (short)f2bf(fmaxf(fmaf(bf2f((u16)v1[j]), scsh[c1][0], scsh[c1][1]), 0.f));
    }
    const int g0 = (cq * 2) ^ (pos & 7), g1g = (cq * 2 + 1) ^ (pos & 7);
    *reinterpret_cast<short8b*>(&feat_l[u][pos * 64 + g0 * 8]) = p0;
    *reinterpret_cast<short8b*>(&feat_l[u][pos * 64 + g1g * 8]) = p1;
  }

  // ---- qkv via MFMA, f32 results straight into LDS ----
  const int dq = lane & 15, lk = lane >> 4;
  short8b afr[2];
#pragma unroll
  for (int ch = 0; ch < 2; ++ch) {
    const int kg = ch * 4 + lk;
    afr[ch] = *reinterpret_cast<const short8b*>(&feat_l[u][dq * 64 + ((kg ^ (dq & 7)) * 8)]);
  }
#pragma unroll
  for (int ct = 0; ct < 12; ++ct) {
    f32x4 d = {0.f, 0.f, 0.f, 0.f};
#pragma unroll
    for (int ch = 0; ch < 2; ++ch) {
      short8b bfr = *reinterpret_cast<const short8b*>(&wqkvT[(ct * 16 + dq) * 64 + ch * 32 + lk * 8]);
      d = __builtin_amdgcn_mfma_f32_16x16x32_bf16(afr[ch], bfr, d, 0, 0, 0);
    }
    if (ct < 4) {
      float* dst = Wf + ct * 280;
#pragma unroll
      for (int r = 0; r < 4; ++r) dst[(lk * 4 + r) * 17 + dq] = d[r] * 0.25f;
    } else {
      float* dst = (ct < 8) ? (Wf + 1120 + (ct - 4) * 264) : (Wf + 2176 + (ct - 8) * 264);
      const int cp = dq ^ (lk << 2);
#pragma unroll
      for (int r = 0; r < 4; ++r) dst[(lk * 4 + r) * 16 + cp] = d[r];
    }
  }

  // ---- attention core: thread = (head n=lk, query pos qp=dq) ----
  const int n = lk, qp = dq;
  const int qi = qp >> 2, qj = qp & 3;
  float q_[16];
  {
    const float* qb = Wf + n * 280 + qp * 17;
#pragma unroll
    for (int d2 = 0; d2 < 16; ++d2) q_[d2] = qb[d2];
  }
  float rwq[4], rhq[4];
  {
    const float* rwp = relw + (3 - qj) * 16;
    const float* rhp = relh + (3 - qi) * 16;
#pragma unroll
    for (int m = 0; m < 4; ++m) {
      float a1 = 0.f, a2 = 0.f;
#pragma unroll
      for (int d2 = 0; d2 < 16; ++d2) {
        a1 = fmaf(q_[d2], rwp[m * 16 + d2], a1);
        a2 = fmaf(q_[d2], rhp[m * 16 + d2], a2);
      }
      rwq[m] = a1; rhq[m] = a2;
    }
  }
  float lo[16]; float mx = -1e30f;
  const float* kbase = Wf + 1120 + n * 264;
#pragma unroll
  for (int kp = 0; kp < 16; ++kp) {
    const float4* kr = reinterpret_cast<const float4*>(kbase + kp * 16);
    float s = rwq[kp & 3] + rhq[kp >> 2];
#pragma unroll
    for (int g = 0; g < 4; ++g) {
      float4 kv = kr[g];
      const int lg = (g ^ (kp >> 2)) * 4;
      s = fmaf(q_[lg], kv.x, s); s = fmaf(q_[lg + 1], kv.y, s);
      s = fmaf(q_[lg + 2], kv.z, s); s = fmaf(q_[lg + 3], kv.w, s);
    }
    lo[kp] = s; mx = fmaxf(mx, s);
  }
  float ssum = 0.f;
#pragma unroll
  for (int kp = 0; kp < 16; ++kp) { float e = __expf(lo[kp] - mx); lo[kp] = e; ssum += e; }
  const float inv = 1.0f / ssum;
  float ov[16];
#pragma unroll
  for (int j = 0; j < 16; ++j) ov[j] = 0.f;
  const float* vbase = Wf + 2176 + n * 264;
#pragma unroll
  for (int kp = 0; kp < 16; ++kp) {
    const float4* vr = reinterpret_cast<const float4*>(vbase + kp * 16);
    const float wgt = lo[kp];
#pragma unroll
    for (int g = 0; g < 4; ++g) {
      float4 vv = vr[g];
      const int lg = (g ^ (kp >> 2)) * 4;
      ov[lg] = fmaf(wgt, vv.x, ov[lg]);
      ov[lg + 1] = fmaf(wgt, vv.y, ov[lg + 1]);
      ov[lg + 2] = fmaf(wgt, vv.z, ov[lg + 2]);
      ov[lg + 3] = fmaf(wgt, vv.w, ov[lg + 3]);
    }
  }
#pragma unroll
  for (int j = 0; j < 16; ++j) ov[j] *= inv;

  // bf16 output write
  {
    short8b o0, o1;
#pragma unroll
    for (int j = 0; j < 8; ++j) {
      o0[j] = (short)f2bf(ov[j]);
      o1[j] = (short)f2bf(ov[8 + j]);
    }
    u16* dstb = buf + b * 1024 + qp * 64 + (n << 4);
    *reinterpret_cast<short8b*>(dstb) = o0;
    *reinterpret_cast<short8b*>(dstb + 8) = o1;
  }

  // ---- fused stats2: per-wave LDS transpose (reuse Wf), column sums ----
  {
    float* fl = Wf;                                       // [16 pos][69]
#pragma unroll
    for (int j = 0; j < 16; ++j) fl[qp * 69 + n * 16 + j] = ov[j];
    const int c = lane;                                   // 0..63 channel
    float s = 0.f, s2 = 0.f;
#pragma unroll
    for (int pos = 0; pos < 16; ++pos) {
      float v = fl[pos * 69 + c];
      s += v; s2 = fmaf(v, v, s2);
    }
    atomicAdd(&pstA[c], s);
    atomicAdd(&pstA[64 + c], s2);
  }
  __syncthreads();
  if (t < 128) partials2[(size_t)blockIdx.x * 128 + t] = pstA[t];
}

// ---------- conv3: BN2+relu(buf bf16 NHWC) -> y3b (bf16 NCHW) + fused stats3 ----------
// grid (512, 2): 256 rows per WG, o-half per blockIdx.y. Wave tile 64o x 128pos.
__global__ __launch_bounds__(256, 2) void conv3_kernel(const u16* __restrict__ src,
                                                       const u16* __restrict__ wp,
                                                       const float* __restrict__ acc2,
                                                       const float* __restrict__ g2,
                                                       const float* __restrict__ b2,
                                                       u16* __restrict__ y3b,
                                                       float* __restrict__ partials3) {
  __shared__ __align__(16) u16 featB[257 * 64];     // bf16 [256 rows][64ch] swizzled; row 256 = zeros
  __shared__ __align__(16) u16 ldsW[2][128 * 64];   // [o 128][64 k] per tap, swizzled
  __shared__ float scsh[128];
  const int t = threadIdx.x;
  const int lane = t & 63, w = t >> 6;
  const int lrow = lane & 15, lk = lane >> 4;
  const int wm = w >> 1, wn = w & 1;
  const int Nbase = blockIdx.x * 256;
  const int ohalf = blockIdx.y;

  int rel[9];
  {
    const int pi = lrow >> 2, pj = lrow & 3;
#pragma unroll
    for (int tap = 0; tap < 9; ++tap) {
      const int ti = tap / 3, tj = tap - ti * 3;
      int si = pi + ti - 1, sj = pj + tj - 1;
      bool valid = ((unsigned)si < 4u) && ((unsigned)sj < 4u);
      rel[tap] = valid ? ((si * 4 + sj) << 7) : (1 << 24);
    }
  }

  if (t < 64) {
    float sh; float sc = bn_scale(acc2, g2, b2, 64, t, sh);
    scsh[t * 2] = sc; scsh[t * 2 + 1] = sh;
  }

  // W tap0 -> ldsW[0] (no scsh dependency)
  const int so = t >> 1, shalf = t & 1, so7 = so & 7;
  {
    const u16* wsrc = wp + ohalf * 8192 + so * 64 + shalf * 32;
    uint4 w0 = *reinterpret_cast<const uint4*>(wsrc);
    uint4 w1 = *reinterpret_cast<const uint4*>(wsrc + 8);
    uint4 w2 = *reinterpret_cast<const uint4*>(wsrc + 16);
    uint4 w3v = *reinterpret_cast<const uint4*>(wsrc + 24);
    char* dst = (char*)ldsW[0] + so * 128;
    const int gb = shalf * 4;
    *reinterpret_cast<uint4*>(dst + (((gb + 0) ^ so7) << 4)) = w0;
    *reinterpret_cast<uint4*>(dst + (((gb + 1) ^ so7) << 4)) = w1;
    *reinterpret_cast<uint4*>(dst + (((gb + 2) ^ so7) << 4)) = w2;
    *reinterpret_cast<uint4*>(dst + (((gb + 3) ^ so7) << 4)) = w3v;
  }
  __syncthreads();

  // featB staging (BN2+relu): thread t -> row t
  {
    const u16* srow = src + (size_t)(Nbase + t) * 64;
    char* drow = (char*)featB + t * 128;
    const int r7 = t & 7;
#pragma unroll
    for (int g = 0; g < 8; ++g) {
      short8b v = *reinterpret_cast<const short8b*>(srow + g * 8);
      short8b pk;
#pragma unroll
      for (int j = 0; j < 8; ++j) {
        const int c = g * 8 + j;
        pk[j] = (short)f2bf(fmaxf(fmaf(bf2f((u16)v[j]), scsh[c * 2], scsh[c * 2 + 1]), 0.f));
      }
      *reinterpret_cast<short8b*>(drow + ((g ^ r7) << 4)) = pk;
    }
  }
  if (t < 8) *reinterpret_cast<uint4*>((char*)featB + 32768 + t * 16) = uint4{0, 0, 0, 0};

  // W tap1 -> regs
  uint4 r0, r1, r2, r3v;
  {
    const u16* wsrc = wp + 16384 + ohalf * 8192 + so * 64 + shalf * 32;
    r0 = *reinterpret_cast<const uint4*>(wsrc);
    r1 = *reinterpret_cast<const uint4*>(wsrc + 8);
    r2 = *reinterpret_cast<const uint4*>(wsrc + 16);
    r3v = *reinterpret_cast<const uint4*>(wsrc + 24);
  }
  __syncthreads();

  f32x4 acc[4][8] = {};
  const char* fB = (const char*)featB;
  const int swzA0 = (lk << 4) ^ ((lrow & 7) << 4);
  const int swzA1 = (64 | (lk << 4)) ^ ((lrow & 7) << 4);

#pragma unroll
  for (int tap = 0; tap < 9; ++tap) {
    const int cur = tap & 1;
    const char* lW = (const char*)ldsW[cur];
    short8b aw0[4], aw1[4];
#pragma unroll
    for (int m = 0; m < 4; ++m) {
      const int rowoff = (wm * 64 + m * 16 + lrow) << 7;
      aw0[m] = *reinterpret_cast<const short8b*>(lW + rowoff + swzA0);
      aw1[m] = *reinterpret_cast<const short8b*>(lW + rowoff + swzA1);
    }
#pragma unroll
    for (int n = 0; n < 8; ++n) {
      int ad0 = ((wn * 128 + n * 16) << 7) + rel[tap];
      ad0 = ad0 < 32768 ? ad0 : 32768;
      const int swz = (ad0 >> 3) & 0x70;
      short8b bf0 = *reinterpret_cast<const short8b*>(fB + ad0 + ((lk << 4) ^ swz));
      short8b bf1 = *reinterpret_cast<const short8b*>(fB + ad0 + ((64 | (lk << 4)) ^ swz));
#pragma unroll
      for (int m = 0; m < 4; ++m) {
        acc[m][n] = __builtin_amdgcn_mfma_f32_16x16x32_bf16(aw0[m], bf0, acc[m][n], 0, 0, 0);
        acc[m][n] = __builtin_amdgcn_mfma_f32_16x16x32_bf16(aw1[m], bf1, acc[m][n], 0, 0, 0);
      }
    }
    if (tap < 8) {
      char* dst = (char*)ldsW[cur ^ 1] + so * 128;
      const int gb = shalf * 4;
      *reinterpret_cast<uint4*>(dst + (((gb + 0) ^ so7) << 4)) = r0;
      *reinterpret_cast<uint4*>(dst + (((gb + 1) ^ so7) << 4)) = r1;
      *reinterpret_cast<uint4*>(dst + (((gb + 2) ^ so7) << 4)) = r2;
      *reinterpret_cast<uint4*>(dst + (((gb + 3) ^ so7) << 4)) = r3v;
      if (tap < 7) {
        const u16* wsrc = wp + (tap + 2) * 16384 + ohalf * 8192 + so * 64 + shalf * 32;
        r0 = *reinterpret_cast<const uint4*>(wsrc);
        r1 = *reinterpret_cast<const uint4*>(wsrc + 8);
        r2 = *reinterpret_cast<const uint4*>(wsrc + 16);
        r3v = *reinterpret_cast<const uint4*>(wsrc + 24);
      }
    }
    __syncthreads();
  }

  // bf16 NCHW stores: D[o][pos]
#pragma unroll
  for (int m = 0; m < 4; ++m) {
    const int o = ohalf * 128 + wm * 64 + m * 16 + lk * 4;
#pragma unroll
    for (int n = 0; n < 8; ++n) {
      const int colg = Nbase + wn * 128 + n * 16 + lrow;
      const int b = colg >> 4, p = colg & 15;
      u16* dst = y3b + (size_t)b * 4096 + (size_t)o * 16 + p;
#pragma unroll
      for (int r = 0; r < 4; ++r)
        dst[r * 16] = f2bf(acc[m][n][r]);
    }
  }

  // fused stats3 partials (channel-local to o-half)
  float* pst = reinterpret_cast<float*>(featB);     // [S 128][S2 128]
  pst[t] = 0.f;
  __syncthreads();
#pragma unroll
  for (int m = 0; m < 4; ++m) {
#pragma unroll
    for (int r = 0; r < 4; ++r) {
      float s = 0.f, s2 = 0.f;
#pragma unroll
      for (int n = 0; n < 8; ++n) {
        float v = acc[m][n][r];
        s += v; s2 = fmaf(v, v, s2);
      }
      s += __shfl_xor(s, 1); s2 += __shfl_xor(s2, 1);
      s += __shfl_xor(s, 2); s2 += __shfl_xor(s2, 2);
      s += __shfl_xor(s, 4); s2 += __shfl_xor(s2, 4);
      s += __shfl_xor(s, 8); s2 += __shfl_xor(s2, 8);
      if (lrow == 0) {
        const int ch = wm * 64 + m * 16 + lk * 4 + r;
        atomicAdd(&pst[ch], s);
        atomicAdd(&pst[128 + ch], s2);
      }
    }
  }
  __syncthreads();
  partials3[((size_t)(ohalf * 512 + blockIdx.x)) * 256 + t] = pst[t];
}

// ---------- reduce conv3 partials -> acc3 ([S 256][S2 256]) ----------
__global__ __launch_bounds__(256) void reduce3_kernel(const float* __restrict__ p,
                                                      float* __restrict__ acc3) {
  const int c2 = blockIdx.x, t = threadIdx.x;       // 0..511
  const int kind = c2 >> 8, c = c2 & 255;
  const int h = c >> 7, chl = c & 127;
  float s = 0.f;
  for (int i = t; i < 512; i += 256)
    s += p[((size_t)(h * 512 + i)) * 256 + kind * 128 + chl];
#pragma unroll
  for (int off = 32; off > 0; off >>= 1) s += __shfl_down(s, off);
  __shared__ float red[4];
  if ((t & 63) == 0) red[t >> 6] = s;
  __syncthreads();
  if (t == 0) acc3[kind * 256 + c] = red[0] + red[1] + red[2] + red[3];
}

// ---------- BN3 + relu: y3b (bf16) -> d_out (fp32) ----------
__global__ __launch_bounds__(256) void final_kernel(const u16* __restrict__ y3b,
                                                    float* __restrict__ out,
                                                    const float* __restrict__ acc3,
                                                    const float* __restrict__ g3,
                                                    const float* __restrict__ b3) {
  const size_t i = ((size_t)blockIdx.x * 256 + threadIdx.x) * 8;
  const int c = (int)((i >> 4) & 255);
  float sh; const float sc = bn_scale(acc3, g3, b3, 256, c, sh);
  short8b v = *reinterpret_cast<const short8b*>(y3b + i);
  float4 o0, o1;
  o0.x = fmaxf(fmaf(bf2f((u16)v[0]), sc, sh), 0.f);
  o0.y = fmaxf(fmaf(bf2f((u16)v[1]), sc, sh), 0.f);
  o0.z = fmaxf(fmaf(bf2f((u16)v[2]), sc, sh), 0.f);
  o0.w = fmaxf(fmaf(bf2f((u16)v[3]), sc, sh), 0.f);
  o1.x = fmaxf(fmaf(bf2f((u16)v[4]), sc, sh), 0.f);
  o1.y = fmaxf(fmaf(bf2f((u16)v[5]), sc, sh), 0.f);
  o1.z = fmaxf(fmaf(bf2f((u16)v[6]), sc, sh), 0.f);
  o1.w = fmaxf(fmaf(bf2f((u16)v[7]), sc, sh), 0.f);
  *reinterpret_cast<float4*>(out + i) = o0;
  *reinterpret_cast<float4*>(out + i + 4) = o1;
}

extern "C" void kernel_launch(void* const* d_in, const int* in_sizes, int n_in,
                              void* d_out, int out_size, void* d_ws, size_t ws_size,
                              hipStream_t stream) {
  const float* x   = (const float*)d_in[0];
  const float* w1  = (const float*)d_in[1];
  const float* g1  = (const float*)d_in[3];
  const float* bb1 = (const float*)d_in[4];
  const float* wq  = (const float*)d_in[5];
  const float* wk  = (const float*)d_in[6];
  const float* wv  = (const float*)d_in[7];
  const float* rw  = (const float*)d_in[8];
  const float* rh  = (const float*)d_in[9];
  const float* g2  = (const float*)d_in[10];
  const float* bb2 = (const float*)d_in[11];
  const float* w3  = (const float*)d_in[12];
  const float* g3  = (const float*)d_in[14];
  const float* bb3 = (const float*)d_in[15];
  float* out = (float*)d_out;
  float* ws  = (float*)d_ws;

  u16*   bufb   = (u16*)ws;                 // 8,388,608 u16
  u16*   y3b    = bufb + 8388608;           // 33,554,432 u16
  u16*   wp1    = y3b + 33554432;           // 46080
  u16*   wp3    = wp1 + 46080;              // 147456
  u16*   wqkvT  = wp3 + 147456;             // 12288
  // u16 total above = 42,148,864 = 21,074,432 floats
  float* acc1   = ws + 21074432;            // 128
  float* acc2   = acc1 + 128;               // 128
  float* acc3   = acc2 + 128;               // 512
  float* part1  = acc3 + 512;               // 512*128   = 65536
  float* part2  = part1 + 65536;            // 2048*128  = 262144
  float* part3  = part2 + 262144;           // 1024*256  = 262144

  prep_kernel<<<804, 256, 0, stream>>>(w1, w3, wq, wk, wv, wp1, wp3, wqkvT);
  conv1_kernel<<<512, 256, 0, stream>>>(x, wp1, bufb, part1);
  reduce12_kernel<<<128, 256, 0, stream>>>(part1, acc1, 512);
  attn_kernel<<<2048, 256, 0, stream>>>(bufb, wqkvT, rw, rh, acc1, g1, bb1, part2);
  reduce12_kernel<<<128, 256, 0, stream>>>(part2, acc2, 2048);
  conv3_kernel<<<dim3(512, 2), 256, 0, stream>>>(bufb, wp3, acc2, g2, bb2, y3b, part3);
  reduce3_kernel<<<512, 256, 0, stream>>>(part3, acc3);
  final_kernel<<<16384, 256, 0, stream>>>(y3b, out, acc3, g3, bb3);
}